// Round 11
// baseline (1129.146 us; speedup 1.0000x reference)
//
#include <hip/hip_runtime.h>
#include <math.h>

#define NPAD 65

// ---------- small device helpers ----------
__device__ __forceinline__ float leaky(float x) { return x > 0.f ? x : 0.01f * x; }
__device__ __forceinline__ float eluf(float x)  { return x > 0.f ? x : (__expf(x) - 1.f); }
__device__ __forceinline__ float sigm(float x)  { return 1.f / (1.f + __expf(-x)); }
__device__ __forceinline__ float tanhfast(float x) { return 1.f - 2.f / (__expf(2.f * x) + 1.f); }

__device__ __forceinline__ float bcastf(float v, int k) {
    return __uint_as_float((unsigned)__builtin_amdgcn_readlane((int)__float_as_uint(v), k));
}
__device__ __forceinline__ int bcasti(int v, int k) {
    return __builtin_amdgcn_readlane(v, k);
}
__device__ __forceinline__ float wredsum(float v) {
    #pragma unroll
    for (int off = 32; off; off >>= 1) v += __shfl_xor(v, off);
    return v;
}
__device__ __forceinline__ float wredmax(float v) {
    #pragma unroll
    for (int off = 32; off; off >>= 1) v = fmaxf(v, __shfl_xor(v, off));
    return v;
}

// ================= CSR build =================
__global__ __launch_bounds__(256) void k_hist(const int* __restrict__ ei, int* __restrict__ deg, int E_) {
    int e = blockIdx.x * 256 + threadIdx.x;
    if (e < E_) atomicAdd(&deg[ei[E_ + e]], 1);
}

__global__ __launch_bounds__(256) void k_scan1(const int* __restrict__ deg, int* __restrict__ bsum, int N_) {
    __shared__ int s[256];
    int i = blockIdx.x * 256 + threadIdx.x;
    s[threadIdx.x] = (i < N_) ? deg[i] : 0;
    __syncthreads();
    for (int off = 128; off; off >>= 1) {
        if (threadIdx.x < off) s[threadIdx.x] += s[threadIdx.x + off];
        __syncthreads();
    }
    if (threadIdx.x == 0) bsum[blockIdx.x] = s[0];
}

// parallel exclusive scan of block sums (single block, chunked w/ carry)
__global__ __launch_bounds__(512) void k_scan2(int* __restrict__ bsum, int nb) {
    __shared__ int s[512];
    __shared__ int carry_s;
    if (threadIdx.x == 0) carry_s = 0;
    __syncthreads();
    for (int base = 0; base < nb; base += 512) {
        int t = threadIdx.x;
        int idx = base + t;
        int v = (idx < nb) ? bsum[idx] : 0;
        s[t] = v;
        __syncthreads();
        #pragma unroll
        for (int off = 1; off < 512; off <<= 1) {
            int u = (t >= off) ? s[t - off] : 0;
            __syncthreads();
            s[t] += u;
            __syncthreads();
        }
        int carry = carry_s;
        if (idx < nb) bsum[idx] = carry + s[t] - v;   // exclusive
        __syncthreads();
        if (t == 0) carry_s = carry + s[511];
        __syncthreads();
    }
}

__global__ __launch_bounds__(256) void k_scan3(const int* __restrict__ deg, const int* __restrict__ bsum,
                                               int* __restrict__ row, int* __restrict__ cur, int N_, int E_) {
    __shared__ int s[256];
    int i = blockIdx.x * 256 + threadIdx.x;
    int d = (i < N_) ? deg[i] : 0;
    s[threadIdx.x] = d;
    __syncthreads();
    for (int off = 1; off < 256; off <<= 1) {
        int v = (threadIdx.x >= off) ? s[threadIdx.x - off] : 0;
        __syncthreads();
        s[threadIdx.x] += v;
        __syncthreads();
    }
    if (i < N_) {
        int ex = bsum[blockIdx.x] + s[threadIdx.x] - d;
        row[i] = ex; cur[i] = ex;
    }
    if (i == N_ - 1) row[N_] = E_;
}

__global__ __launch_bounds__(256) void k_scatter(const int* __restrict__ ei, int* __restrict__ cur,
                                                 int* __restrict__ csrc, int* __restrict__ ceid, int E_) {
    int e = blockIdx.x * 256 + threadIdx.x;
    if (e >= E_) return;
    int dst = ei[E_ + e];
    int slot = atomicAdd(&cur[dst], 1);
    csrc[slot] = ei[e];
    ceid[slot] = e;
}

__global__ __launch_bounds__(256) void k_gbounds(const int* __restrict__ batch, int* __restrict__ gst,
                                                 int N_, int G_) {
    int i = blockIdx.x * 256 + threadIdx.x;
    if (i >= N_) return;
    int b = batch[i];
    int prev = (i == 0) ? -1 : batch[i - 1];
    for (int g = prev + 1; g <= b; ++g) gst[g] = i;
    if (i == N_ - 1) { for (int g = b + 1; g <= G_; ++g) gst[g] = N_; }
}

// ---------- dual dense64: one raw-tile load, two matmuls, TWO LDS tiles ----------
__global__ __launch_bounds__(256) void k_dense64_dual(
    const float* __restrict__ in,
    const float* __restrict__ w1, const float* __restrict__ b1,
    const float* __restrict__ w2, const float* __restrict__ b2,
    float* __restrict__ out1, float* __restrict__ out2, int M,
    const float* __restrict__ dva, float* __restrict__ dsout)
{
    __shared__ float ti[64 * NPAD];   // input tile, then out2 tile
    __shared__ float t1[64 * NPAD];   // out1 tile
    int r0 = blockIdx.x * 64;
    for (int i = threadIdx.x; i < 4096; i += 256) {
        int r = i >> 6, c = i & 63; int gr = r0 + r;
        ti[r * NPAD + c] = (gr < M) ? in[(size_t)gr * 64 + c] : 0.f;
    }
    __syncthreads();
    int n = threadIdx.x & 63;
    int jl = __builtin_amdgcn_readfirstlane((threadIdx.x >> 6) << 4);
    float a1[16], a2[16];
    #pragma unroll
    for (int jj = 0; jj < 16; ++jj) { a1[jj] = b1[jl + jj]; a2[jj] = b2[jl + jj]; }
    for (int kc = 0; kc < 64; kc += 16) {
        float xr[16];
        #pragma unroll
        for (int i = 0; i < 16; ++i) xr[i] = ti[n * NPAD + kc + i];
        #pragma unroll
        for (int jj = 0; jj < 16; ++jj) {
            const float* wr1 = w1 + (jl + jj) * 64 + kc;
            const float* wr2 = w2 + (jl + jj) * 80 + kc;
            #pragma unroll
            for (int i = 0; i < 16; ++i) {
                a1[jj] = fmaf(wr1[i], xr[i], a1[jj]);
                a2[jj] = fmaf(wr2[i], xr[i], a2[jj]);
            }
        }
    }
    __syncthreads();          // all reads of ti done before reuse as out2 tile
    #pragma unroll
    for (int jj = 0; jj < 16; ++jj) {
        t1[n * NPAD + jl + jj] = leaky(a1[jj]);
        ti[n * NPAD + jl + jj] = a2[jj];
    }
    __syncthreads();
    for (int i = threadIdx.x; i < 4096; i += 256) {
        int r = i >> 6, c = i & 63; int gr = r0 + r;
        if (gr < M) {
            out1[(size_t)gr * 64 + c] = t1[r * NPAD + c];
            out2[(size_t)gr * 64 + c] = ti[r * NPAD + c];
        }
    }
    if (dsout != nullptr) {
        int wv = threadIdx.x >> 6;          // 0..3, rows wv*16..wv*16+15
        float wval = dva[n];
        #pragma unroll 4
        for (int q = 0; q < 16; ++q) {
            int r = (wv << 4) + q; int gr = r0 + r;
            float pv = wredsum(t1[r * NPAD + n] * wval);
            if (n == 0 && gr < M) dsout[gr] = pv;
        }
    }
}

// ---------- GATE layer: persistent waves, grid-stride over dst nodes ----------
// Short-block churn capped avg occupancy at ~64%; 2048 resident blocks with a
// node loop keep waves resident and the gather pipeline full.
#define GDOT(acc, A0, A1, A2, A3) \
    acc = fmaf(A0.x, w2[0], acc);  acc = fmaf(A0.y, w2[1], acc);  \
    acc = fmaf(A0.z, w2[2], acc);  acc = fmaf(A0.w, w2[3], acc);  \
    acc = fmaf(A1.x, w2[4], acc);  acc = fmaf(A1.y, w2[5], acc);  \
    acc = fmaf(A1.z, w2[6], acc);  acc = fmaf(A1.w, w2[7], acc);  \
    acc = fmaf(A2.x, w2[8], acc);  acc = fmaf(A2.y, w2[9], acc);  \
    acc = fmaf(A2.z, w2[10], acc); acc = fmaf(A2.w, w2[11], acc); \
    acc = fmaf(A3.x, w2[12], acc); acc = fmaf(A3.y, w2[13], acc); \
    acc = fmaf(A3.z, w2[14], acc); acc = fmaf(A3.w, w2[15], acc);

__global__ __launch_bounds__(256, 4) void k_gate_gather(
    const float* __restrict__ u, const float* __restrict__ ea,
    const int* __restrict__ row, const int* __restrict__ csrc, const int* __restrict__ ceid,
    const float* __restrict__ wnl,
    const float* __restrict__ gaw, const float* __restrict__ gab,
    const float* __restrict__ sarr, float* __restrict__ Agg, int N_)
{
    int tw = (blockIdx.x * 256 + threadIdx.x) >> 6;   // global wave id
    int nw = (gridDim.x * 256) >> 6;                  // total waves
    int lane = threadIdx.x & 63;
    float w2[16];
    #pragma unroll
    for (int k = 0; k < 16; ++k) w2[k] = wnl[lane * 80 + 64 + k];
    float g2 = gaw[64 + lane];
    float gb = gab[0];
    for (int wid = tw; wid < N_; wid += nw) {
    float sdst = sarr[wid];
    int beg = row[wid], end = row[wid + 1];
    float m = -INFINITY, d = 0.f, S = 0.f;
    for (int cs = beg; cs < end; cs += 64) {
        int cnt = min(64, end - cs);
        int src_l = 0, eid_l = 0;
        if (lane < cnt) { src_l = csrc[cs + lane]; eid_l = ceid[cs + lane]; }
        int cnt2 = (cnt + 1) & ~1;
        // prefetch batch 0 (edges 0,1); padded slot duplicates edge 0
        int j1 = (1 < cnt) ? 1 : 0;
        int s0 = bcasti(src_l, 0), s1 = bcasti(src_l, j1);
        int e0 = bcasti(eid_l, 0), e1 = bcasti(eid_l, j1);
        float u0 = u[(size_t)s0 * 64 + lane];
        float u1 = u[(size_t)s1 * 64 + lane];
        const float4* p0 = (const float4*)(ea + (size_t)e0 * 16);
        const float4* p1 = (const float4*)(ea + (size_t)e1 * 16);
        float4 a00 = p0[0], a01 = p0[1], a02 = p0[2], a03 = p0[3];
        float4 a10 = p1[0], a11 = p1[1], a12 = p1[2], a13 = p1[3];
        for (int l = 0; l < cnt2; l += 2) {
            // issue next batch's loads before current batch's compute chain
            int ln0 = (l + 2 < cnt) ? l + 2 : l;
            int ln1 = (l + 3 < cnt) ? l + 3 : l;
            int ns0 = bcasti(src_l, ln0), ns1 = bcasti(src_l, ln1);
            int ne0 = bcasti(eid_l, ln0), ne1 = bcasti(eid_l, ln1);
            float nu0 = u[(size_t)ns0 * 64 + lane];
            float nu1 = u[(size_t)ns1 * 64 + lane];
            const float4* q0 = (const float4*)(ea + (size_t)ne0 * 16);
            const float4* q1 = (const float4*)(ea + (size_t)ne1 * 16);
            float4 b00 = q0[0], b01 = q0[1], b02 = q0[2], b03 = q0[3];
            float4 b10 = q1[0], b11 = q1[1], b12 = q1[2], b13 = q1[3];
            // compute current batch
            float acc0 = u0, acc1 = u1;
            GDOT(acc0, a00, a01, a02, a03)
            GDOT(acc1, a10, a11, a12, a13)
            float xj0 = leaky(acc0), xj1 = leaky(acc1);
            float t0 = xj0 * g2, t1 = xj1 * g2;
            #pragma unroll
            for (int off = 32; off; off >>= 1) {
                t0 += __shfl_xor(t0, off);
                t1 += __shfl_xor(t1, off);
            }
            float sc0 = leaky(sdst + t0 + gb);
            float sc1 = (l + 1 < cnt) ? leaky(sdst + t1 + gb) : -INFINITY;
            float mn = fmaxf(m, fmaxf(sc0, sc1));
            float c = __expf(m - mn);
            float q0e = __expf(sc0 - mn), q1e = __expf(sc1 - mn);
            S = S * c;
            S = fmaf(q0e, xj0, S); S = fmaf(q1e, xj1, S);
            d = d * c + (q0e + q1e);
            m = mn;
            u0 = nu0; u1 = nu1;
            a00 = b00; a01 = b01; a02 = b02; a03 = b03;
            a10 = b10; a11 = b11; a12 = b12; a13 = b13;
        }
    }
    Agg[(size_t)wid * 64 + lane] = S / (d + 1e-16f);
    }
}

// ---------- GAT layer: persistent waves, grid-stride over dst nodes ----------
__global__ __launch_bounds__(256) void k_gat_gather(
    const int* __restrict__ row, const int* __restrict__ csrc,
    const float* __restrict__ x, const float* __restrict__ sarr,
    const float* __restrict__ tarr, const float* __restrict__ cb,
    float* __restrict__ Agg, int N_)
{
    int tw = (blockIdx.x * 256 + threadIdx.x) >> 6;
    int nw = (gridDim.x * 256) >> 6;
    int lane = threadIdx.x & 63;
    float cbv = cb[0];
    for (int wid = tw; wid < N_; wid += nw) {
    float sdst = sarr[wid];
    int beg = row[wid], end = row[wid + 1];
    float m = -INFINITY, d = 0.f, S = 0.f;
    for (int cs = beg; cs < end; cs += 64) {
        int cnt = min(64, end - cs);
        int src_l = 0;
        if (lane < cnt) src_l = csrc[cs + lane];
        // issue first row-group loads before the score chain
        int s0 = bcasti(src_l, 0), s1 = bcasti(src_l, 1);
        int s2 = bcasti(src_l, 2), s3 = bcasti(src_l, 3);
        float r0 = x[(size_t)s0 * 64 + lane];
        float r1 = x[(size_t)s1 * 64 + lane];
        float r2 = x[(size_t)s2 * 64 + lane];
        float r3 = x[(size_t)s3 * 64 + lane];
        float sc_l = -INFINITY;
        if (lane < cnt) sc_l = leaky(sdst + tarr[src_l] + cbv);
        float cmax = wredmax(sc_l);
        float mn = fmaxf(m, cmax);
        float c = __expf(m - mn);
        float w_l = __expf(sc_l - mn);   // 0 for lanes >= cnt
        d = d * c + wredsum(w_l);
        S *= c;
        int cnt4 = (cnt + 3) & ~3;
        for (int l = 0; l < cnt4; l += 4) {
            int ln = (l + 4 < cnt4) ? l + 4 : 0;
            int t0 = bcasti(src_l, ln),     t1 = bcasti(src_l, ln + 1);
            int t2 = bcasti(src_l, ln + 2), t3 = bcasti(src_l, ln + 3);
            float p0 = x[(size_t)t0 * 64 + lane];
            float p1 = x[(size_t)t1 * 64 + lane];
            float p2 = x[(size_t)t2 * 64 + lane];
            float p3 = x[(size_t)t3 * 64 + lane];
            float w0 = bcastf(w_l, l),     w1 = bcastf(w_l, l + 1);
            float w2 = bcastf(w_l, l + 2), w3 = bcastf(w_l, l + 3);
            S = fmaf(w0, r0, S); S = fmaf(w1, r1, S);
            S = fmaf(w2, r2, S); S = fmaf(w3, r3, S);
            r0 = p0; r1 = p1; r2 = p2; r3 = p3;
        }
        m = mn;
    }
    Agg[(size_t)wid * 64 + lane] = S / (d + 1e-16f);
    }
}

// ---------- fused node update: 128-row tile, 2 rows/lane, SINGLE LDS tile ----------
// (R9 form: VGPR-bound at 4 waves/SIMD; LDS slack unusable — kept as-is.)
// mode 0: sout=dot(hv,dwa), tout=dot(hv,dwb)
// mode 1: sout=dot(0.5(hv+xold),dwa), tout=dot(hv,dwa)
// mode 2: sout=dot(hv,dwa)+dwb[0]
__global__ __launch_bounds__(512, 4) void k_node_update(
    const float* __restrict__ agg, const float* __restrict__ xold,
    const float* __restrict__ wa, const float* __restrict__ ba,
    const float* __restrict__ wih, const float* __restrict__ whh,
    const float* __restrict__ bih, const float* __restrict__ bhh,
    float* __restrict__ xout, int M,
    const float* __restrict__ dwa, const float* __restrict__ dwb,
    float* __restrict__ sout, float* __restrict__ tout, int mode)
{
    __shared__ float tA[128 * NPAD];   // agg tile, then h tile, then out tile
    __shared__ float sc[128 * 17];     // epilogue dot partials
    int r0 = blockIdx.x * 128;
    for (int j = threadIdx.x; j < 2048; j += 512) {
        int r = j >> 4, c4 = (j & 15) << 2; int gr = r0 + r;
        float4 av = make_float4(0.f, 0.f, 0.f, 0.f);
        if (gr < M) av = *(const float4*)(agg + (size_t)gr * 64 + c4);
        int b = r * NPAD + c4;
        tA[b] = av.x; tA[b + 1] = av.y; tA[b + 2] = av.z; tA[b + 3] = av.w;
    }
    __syncthreads();
    int n = threadIdx.x & 63;
    int jl = __builtin_amdgcn_readfirstlane((threadIdx.x >> 6) << 3);  // 0..56
    // clamped per-lane xold row pointers (clamp keeps OOB lanes in-bounds;
    // their outputs are masked at store time)
    int rA = min(r0 + n, M - 1);
    int rB = min(r0 + n + 64, M - 1);
    const float* xrA = xold + (size_t)rA * 64;
    const float* xrB = xold + (size_t)rB * 64;

    // Phase B: h[jl..jl+8) = elu(Agg @ Wa^T + ba), rows n and n+64
    float hvA[8], hvB[8];
    {
        float accA[8], accB[8];
        #pragma unroll
        for (int jj = 0; jj < 8; ++jj) { float bv = ba[jl + jj]; accA[jj] = bv; accB[jj] = bv; }
        for (int kc = 0; kc < 64; kc += 16) {
            float aA[16], aB[16];
            #pragma unroll
            for (int i = 0; i < 16; ++i) {
                aA[i] = tA[n * NPAD + kc + i];
                aB[i] = tA[(n + 64) * NPAD + kc + i];
            }
            #pragma unroll
            for (int jj = 0; jj < 8; ++jj) {
                const float* wr = wa + (jl + jj) * 64 + kc;
                #pragma unroll
                for (int i = 0; i < 16; ++i) {
                    float wv = wr[i];
                    accA[jj] = fmaf(wv, aA[i], accA[jj]);
                    accB[jj] = fmaf(wv, aB[i], accB[jj]);
                }
            }
        }
        #pragma unroll
        for (int jj = 0; jj < 8; ++jj) { hvA[jj] = eluf(accA[jj]); hvB[jj] = eluf(accB[jj]); }
    }
    __syncthreads();          // all phase-B reads of tA done
    #pragma unroll
    for (int jj = 0; jj < 8; ++jj) {
        tA[n * NPAD + jl + jj] = hvA[jj];
        tA[(n + 64) * NPAD + jl + jj] = hvB[jj];
    }
    __syncthreads();          // h tile visible

    // Phase C: GRU. h from LDS, xold streamed from global per chunk.
    float rAc[8], rBc[8], zAc[8], zBc[8], nAc[8], nBc[8], hAc[8], hBc[8];
    #pragma unroll
    for (int jj = 0; jj < 8; ++jj) {
        float brz = bih[jl + jj] + bhh[jl + jj];
        float bz  = bih[64 + jl + jj] + bhh[64 + jl + jj];
        rAc[jj] = brz; rBc[jj] = brz;
        zAc[jj] = bz;  zBc[jj] = bz;
        nAc[jj] = bih[128 + jl + jj]; nBc[jj] = nAc[jj];
        hAc[jj] = bhh[128 + jl + jj]; hBc[jj] = hAc[jj];
    }
    for (int kc = 0; kc < 64; kc += 8) {
        float h0[8], h1[8], x0[8], x1[8];
        float4 ga0 = *(const float4*)(xrA + kc);
        float4 ga1 = *(const float4*)(xrA + kc + 4);
        float4 gb0 = *(const float4*)(xrB + kc);
        float4 gb1 = *(const float4*)(xrB + kc + 4);
        #pragma unroll
        for (int i = 0; i < 8; ++i) {
            h0[i] = tA[n * NPAD + kc + i];
            h1[i] = tA[(n + 64) * NPAD + kc + i];
        }
        x0[0] = ga0.x; x0[1] = ga0.y; x0[2] = ga0.z; x0[3] = ga0.w;
        x0[4] = ga1.x; x0[5] = ga1.y; x0[6] = ga1.z; x0[7] = ga1.w;
        x1[0] = gb0.x; x1[1] = gb0.y; x1[2] = gb0.z; x1[3] = gb0.w;
        x1[4] = gb1.x; x1[5] = gb1.y; x1[6] = gb1.z; x1[7] = gb1.w;
        #pragma unroll
        for (int jj = 0; jj < 8; ++jj) {
            const float* w1 = wih + (jl + jj) * 64 + kc;          // r, input
            const float* w4 = whh + (jl + jj) * 64 + kc;          // r, hidden
            const float* w2 = wih + (64 + jl + jj) * 64 + kc;     // z, input
            const float* w5 = whh + (64 + jl + jj) * 64 + kc;     // z, hidden
            const float* w3 = wih + (128 + jl + jj) * 64 + kc;    // n, input
            const float* w6 = whh + (128 + jl + jj) * 64 + kc;    // n, hidden
            #pragma unroll
            for (int i = 0; i < 8; ++i) {
                float v1 = w1[i], v4 = w4[i], v2 = w2[i];
                float v5 = w5[i], v3 = w3[i], v6 = w6[i];
                rAc[jj] = fmaf(v1, h0[i], rAc[jj]); rAc[jj] = fmaf(v4, x0[i], rAc[jj]);
                rBc[jj] = fmaf(v1, h1[i], rBc[jj]); rBc[jj] = fmaf(v4, x1[i], rBc[jj]);
                zAc[jj] = fmaf(v2, h0[i], zAc[jj]); zAc[jj] = fmaf(v5, x0[i], zAc[jj]);
                zBc[jj] = fmaf(v2, h1[i], zBc[jj]); zBc[jj] = fmaf(v5, x1[i], zBc[jj]);
                nAc[jj] = fmaf(v3, h0[i], nAc[jj]); hAc[jj] = fmaf(v6, x0[i], hAc[jj]);
                nBc[jj] = fmaf(v3, h1[i], nBc[jj]); hBc[jj] = fmaf(v6, x1[i], hBc[jj]);
            }
        }
    }
    // final activation + (optional) fused dot partials; xo reloaded from global
    float xoA[8], xoB[8];
    {
        float4 fA0 = *(const float4*)(xrA + jl), fA1 = *(const float4*)(xrA + jl + 4);
        float4 fB0 = *(const float4*)(xrB + jl), fB1 = *(const float4*)(xrB + jl + 4);
        xoA[0] = fA0.x; xoA[1] = fA0.y; xoA[2] = fA0.z; xoA[3] = fA0.w;
        xoA[4] = fA1.x; xoA[5] = fA1.y; xoA[6] = fA1.z; xoA[7] = fA1.w;
        xoB[0] = fB0.x; xoB[1] = fB0.y; xoB[2] = fB0.z; xoB[3] = fB0.w;
        xoB[4] = fB1.x; xoB[5] = fB1.y; xoB[6] = fB1.z; xoB[7] = fB1.w;
    }
    float paA = 0.f, pbA = 0.f, paB = 0.f, pbB = 0.f;
    #pragma unroll
    for (int jj = 0; jj < 8; ++jj) {
        float r = sigm(rAc[jj]);
        float z = sigm(zAc[jj]);
        float nn = tanhfast(nAc[jj] + r * hAc[jj]);
        float xo = xoA[jj];
        float v = (1.f - z) * nn + z * xo;
        hvA[jj] = fmaxf(v, 0.f);

        float rb = sigm(rBc[jj]);
        float zb = sigm(zBc[jj]);
        float nb_ = tanhfast(nBc[jj] + rb * hBc[jj]);
        float xob = xoB[jj];
        float vb = (1.f - zb) * nb_ + zb * xob;
        hvB[jj] = fmaxf(vb, 0.f);

        if (sout != nullptr) {
            float wav = dwa[jl + jj];
            float wbv = (mode == 0) ? dwb[jl + jj] : wav;
            float a1A = (mode == 1) ? 0.5f * (hvA[jj] + xo)  : hvA[jj];
            float a1B = (mode == 1) ? 0.5f * (hvB[jj] + xob) : hvB[jj];
            paA = fmaf(a1A, wav, paA); pbA = fmaf(hvA[jj], wbv, pbA);
            paB = fmaf(a1B, wav, paB); pbB = fmaf(hvB[jj], wbv, pbB);
        }
    }
    __syncthreads();          // all phase-C reads of tA done
    #pragma unroll
    for (int jj = 0; jj < 8; ++jj) {
        tA[n * NPAD + jl + jj] = hvA[jj];
        tA[(n + 64) * NPAD + jl + jj] = hvB[jj];
    }
    if (sout != nullptr) {
        int w2i = (threadIdx.x >> 6) << 1;              // slot 0..14
        sc[n * 17 + w2i]            = paA;
        sc[n * 17 + w2i + 1]        = pbA;
        sc[(n + 64) * 17 + w2i]     = paB;
        sc[(n + 64) * 17 + w2i + 1] = pbB;
    }
    __syncthreads();
    for (int j = threadIdx.x; j < 2048; j += 512) {
        int r = j >> 4, c4 = (j & 15) << 2; int gr = r0 + r;
        if (gr < M) {
            int b = r * NPAD + c4;
            float4 ov = make_float4(tA[b], tA[b + 1], tA[b + 2], tA[b + 3]);
            *(float4*)(xout + (size_t)gr * 64 + c4) = ov;
        }
    }
    if (sout != nullptr && threadIdx.x < 128) {
        int r = threadIdx.x; int gr = r0 + r;
        if (gr < M) {
            float sa = 0.f, sb = 0.f;
            #pragma unroll
            for (int w = 0; w < 16; w += 2) { sa += sc[r * 17 + w]; sb += sc[r * 17 + w + 1]; }
            if (mode == 2) {
                sout[gr] = sa + dwb[0];
            } else {
                sout[gr] = sa; tout[gr] = sb;
            }
        }
    }
}

// ---------- readout: wave per graph, contiguous segment sum + relu ----------
__global__ __launch_bounds__(256) void k_seg_sum_relu(
    const float* __restrict__ x, const int* __restrict__ gst,
    float* __restrict__ outp, int G_)
{
    int g = (blockIdx.x * 256 + threadIdx.x) >> 6;
    int lane = threadIdx.x & 63;
    if (g >= G_) return;
    float S0 = 0.f, S1 = 0.f, S2 = 0.f, S3 = 0.f;
    int end = gst[g + 1];
    int i = gst[g];
    for (; i + 4 <= end; i += 4) {
        S0 += x[(size_t)i * 64 + lane];
        S1 += x[(size_t)(i + 1) * 64 + lane];
        S2 += x[(size_t)(i + 2) * 64 + lane];
        S3 += x[(size_t)(i + 3) * 64 + lane];
    }
    for (; i < end; ++i) S0 += x[(size_t)i * 64 + lane];
    outp[(size_t)g * 64 + lane] = fmaxf((S0 + S1) + (S2 + S3), 0.f);
}

// ---------- molecule attention: persistent waves, grid-stride over graphs ----------
__global__ __launch_bounds__(256) void k_mol_gather(
    const float* __restrict__ xf, const float* __restrict__ cach,
    const float* __restrict__ stateIn, const int* __restrict__ gst,
    const float* __restrict__ dd,
    const float* __restrict__ maw, const float* __restrict__ mab,
    float* __restrict__ Agg, int G_)
{
    int tw = (blockIdx.x * 256 + threadIdx.x) >> 6;
    int nw = (gridDim.x * 256) >> 6;
    int lane = threadIdx.x & 63;
    float mb = mab[0];
    float mw0 = maw[lane];
    for (int g = tw; g < G_; g += nw) {
    float o = stateIn[(size_t)g * 64 + lane];
    float og = wredsum(o * mw0);
    int beg = gst[g], end = gst[g + 1];
    float m = -INFINITY, d = 0.f, S = 0.f;
    for (int cs = beg; cs < end; cs += 64) {
        int cnt = min(64, end - cs);
        // issue first row-group loads before the score chain
        size_t rb = (size_t)cs * 64 + lane;
        float x0 = xf[rb],      c0 = cach[rb];
        float x1 = xf[rb + 64], c1 = cach[rb + 64];
        float x2 = xf[rb + 128], c2 = cach[rb + 128];
        float x3 = xf[rb + 192], c3 = cach[rb + 192];
        float sc_l = -INFINITY;
        if (lane < cnt) sc_l = leaky(og + dd[cs + lane] + mb);
        float cmax = wredmax(sc_l);
        float mn = fmaxf(m, cmax);
        float c = __expf(m - mn);
        float w_l = __expf(sc_l - mn);   // 0 for lanes >= cnt
        d = d * c + wredsum(w_l);
        S *= c;
        int cnt4 = (cnt + 3) & ~3;
        for (int l = 0; l < cnt4; l += 4) {
            int ln = (l + 4 < cnt4) ? l + 4 : 0;
            size_t rn = (size_t)(cs + ln) * 64 + lane;
            float y0 = xf[rn],       d0 = cach[rn];
            float y1 = xf[rn + 64],  d1 = cach[rn + 64];
            float y2 = xf[rn + 128], d2 = cach[rn + 128];
            float y3 = xf[rn + 192], d3 = cach[rn + 192];
            float w0 = bcastf(w_l, l),     w1 = bcastf(w_l, l + 1);
            float w2 = bcastf(w_l, l + 2), w3 = bcastf(w_l, l + 3);
            S = fmaf(w0, 0.5f * (x0 + c0), S);
            S = fmaf(w1, 0.5f * (x1 + c1), S);
            S = fmaf(w2, 0.5f * (x2 + c2), S);
            S = fmaf(w3, 0.5f * (x3 + c3), S);
            x0 = y0; c0 = d0; x1 = y1; c1 = d1;
            x2 = y2; c2 = d2; x3 = y3; c3 = d3;
        }
        m = mn;
    }
    Agg[(size_t)g * 64 + lane] = S / (d + 1e-16f);
    }
}

// =====================================================================
extern "C" void kernel_launch(void* const* d_in, const int* in_sizes, int n_in,
                              void* d_out, int out_size, void* d_ws, size_t ws_size,
                              hipStream_t stream) {
    const float* raw           = (const float*)d_in[0];
    const int*   ei            = (const int*)d_in[1];
    const float* ea            = (const float*)d_in[2];
    const int*   batch         = (const int*)d_in[3];
    const float* lin1_w        = (const float*)d_in[4];
    const float* lin1_b        = (const float*)d_in[5];
    const float* gate_nl_w     = (const float*)d_in[6];
    const float* gate_nl_b     = (const float*)d_in[7];
    const float* gate_align_w  = (const float*)d_in[8];
    const float* gate_align_b  = (const float*)d_in[9];
    const float* gate_attend_w = (const float*)d_in[10];
    const float* gate_attend_b = (const float*)d_in[11];
    const float* conv_align_w  = (const float*)d_in[12];
    const float* conv_align_b  = (const float*)d_in[13];
    const float* conv_attend_w = (const float*)d_in[14];
    const float* conv_attend_b = (const float*)d_in[15];
    const float* gru_wih       = (const float*)d_in[16];
    const float* gru_whh       = (const float*)d_in[17];
    const float* gru_bih       = (const float*)d_in[18];
    const float* gru_bhh       = (const float*)d_in[19];
    const float* mol_align_w   = (const float*)d_in[20];
    const float* mol_align_b   = (const float*)d_in[21];
    const float* mol_attend_w  = (const float*)d_in[22];
    const float* mol_attend_b  = (const float*)d_in[23];
    const float* mol_wih       = (const float*)d_in[24];
    const float* mol_whh       = (const float*)d_in[25];
    const float* mol_bih       = (const float*)d_in[26];
    const float* mol_bhh       = (const float*)d_in[27];
    const float* lin2_w        = (const float*)d_in[28];
    const float* lin2_b        = (const float*)d_in[29];
    float* out = (float*)d_out;

    const int N = in_sizes[3];
    const int E = in_sizes[1] / 2;
    const int G = out_size;
    const size_t N64 = (size_t)N * 64;
    const size_t G64 = (size_t)G * 64;

    // ---- workspace layout ----
    float* f = (float*)d_ws;
    float* xA    = f;
    float* xB    = xA + N64;
    float* xD    = xB + N64;
    float* Agg   = xD + N64;
    float* u     = Agg + N64;
    float* sN    = u + N64;
    float* tN    = sN + N;
    float* dd    = tN + N;
    float* outS  = dd + N;
    float* outS2 = outS + G64;
    float* aggG  = outS2 + G64;
    int* row  = (int*)(aggG + G64);
    int* csrc = row + (N + 1);
    int* ceid = csrc + E;
    int* bsum = ceid + E;
    int* gst  = bsum + 512;
    int* deg = (int*)Agg;
    int* cur = deg + N;

    const int nb_node64  = (N + 63) / 64;
    const int nb_node128 = (N + 127) / 128;
    const int nb_edge   = (E + 255) / 256;
    const int nb_nodes  = (N + 255) / 256;
    const int nb_waveN  = (N + 3) / 4;
    const int nb_waveG  = (G + 3) / 4;
    const int nb_nodeG  = (G + 127) / 128;
    const int nb_gather = (nb_waveN < 2048) ? nb_waveN : 2048;  // persistent waves
    const int nb_gathG  = (nb_waveG < 2048) ? nb_waveG : 2048;

    // ---- CSR build ----
    hipMemsetAsync(deg, 0, (size_t)N * 4, stream);
    k_hist<<<nb_edge, 256, 0, stream>>>(ei, deg, E);
    k_scan1<<<nb_nodes, 256, 0, stream>>>(deg, bsum, N);
    k_scan2<<<1, 512, 0, stream>>>(bsum, nb_nodes);
    k_scan3<<<nb_nodes, 256, 0, stream>>>(deg, bsum, row, cur, N, E);
    k_scatter<<<nb_edge, 256, 0, stream>>>(ei, cur, csrc, ceid, E);
    k_gbounds<<<nb_nodes, 256, 0, stream>>>(batch, gst, N, G);

    // ---- lin1 + gate node-part in ONE pass (+fused gate align dot -> sN) ----
    k_dense64_dual<<<nb_node64, 256, 0, stream>>>(raw, lin1_w, lin1_b,
                                                  gate_nl_w, gate_nl_b,
                                                  xA, u, N, gate_align_w, sN);

    // ---- layer 0: GATEConv (xA -> xB); emits align dots for GAT layer 0 ----
    k_gate_gather<<<nb_gather, 256, 0, stream>>>(u, ea, row, csrc, ceid,
                                                 gate_nl_w, gate_align_w, gate_align_b,
                                                 sN, Agg, N);
    k_node_update<<<nb_node128, 512, 0, stream>>>(Agg, xA, gate_attend_w, gate_attend_b,
                                                  gru_wih, gru_whh, gru_bih, gru_bhh, xB, N,
                                                  conv_align_w, conv_align_w + 64, sN, tN, 0);

    // ---- GAT layer 0 (xB -> xD); emits align dots for GAT layer 1 ----
    k_gat_gather<<<nb_gather, 256, 0, stream>>>(row, csrc, xB, sN, tN, conv_align_b, Agg, N);
    k_node_update<<<nb_node128, 512, 0, stream>>>(Agg, xB, conv_attend_w, conv_attend_b,
                                                  gru_wih + 12288, gru_whh + 12288,
                                                  gru_bih + 192, gru_bhh + 192, xD, N,
                                                  conv_align_w + 128, conv_align_w + 192, sN, tN, 0);

    // ---- GAT layer 1 (xD -> xA); emits mol dots dd0 -> dd, dd1 -> tN ----
    k_gat_gather<<<nb_gather, 256, 0, stream>>>(row, csrc, xD, sN, tN, conv_align_b + 1, Agg, N);
    k_node_update<<<nb_node128, 512, 0, stream>>>(Agg, xD, conv_attend_w + 4096, conv_attend_b + 64,
                                                  gru_wih + 24576, gru_whh + 24576,
                                                  gru_bih + 384, gru_bhh + 384, xA, N,
                                                  mol_align_w + 64, mol_align_w + 64, dd, tN, 1);

    // ---- molecule readout ----
    k_seg_sum_relu<<<nb_waveG, 256, 0, stream>>>(xA, gst, outS, G);

    // t=0: cached = xD, dots = dd (0.5(xA+xD).maw2)
    k_mol_gather<<<nb_gathG, 256, 0, stream>>>(xA, xD, outS, gst, dd,
                                               mol_align_w, mol_align_b, aggG, G);
    k_node_update<<<nb_nodeG, 512, 0, stream>>>(aggG, outS, mol_attend_w, mol_attend_b,
                                                mol_wih, mol_whh, mol_bih, mol_bhh, outS2, G,
                                                nullptr, nullptr, nullptr, nullptr, 0);
    // t=1: cached = xA, dots = tN (xA.maw2); fused lin2 -> out
    k_mol_gather<<<nb_gathG, 256, 0, stream>>>(xA, xA, outS2, gst, tN,
                                               mol_align_w, mol_align_b, aggG, G);
    k_node_update<<<nb_nodeG, 512, 0, stream>>>(aggG, outS2, mol_attend_w, mol_attend_b,
                                                mol_wih, mol_whh, mol_bih, mol_bhh, outS, G,
                                                lin2_w, lin2_b, out, nullptr, 2);
}

// Round 12
// 1089.642 us; speedup vs baseline: 1.0363x; 1.0363x over previous
//
#include <hip/hip_runtime.h>
#include <math.h>

#define NPAD 65

// ---------- small device helpers ----------
__device__ __forceinline__ float leaky(float x) { return x > 0.f ? x : 0.01f * x; }
__device__ __forceinline__ float eluf(float x)  { return x > 0.f ? x : (__expf(x) - 1.f); }
__device__ __forceinline__ float sigm(float x)  { return 1.f / (1.f + __expf(-x)); }
__device__ __forceinline__ float tanhfast(float x) { return 1.f - 2.f / (__expf(2.f * x) + 1.f); }

__device__ __forceinline__ float bcastf(float v, int k) {
    return __uint_as_float((unsigned)__builtin_amdgcn_readlane((int)__float_as_uint(v), k));
}
__device__ __forceinline__ int bcasti(int v, int k) {
    return __builtin_amdgcn_readlane(v, k);
}
__device__ __forceinline__ float wredsum(float v) {
    #pragma unroll
    for (int off = 32; off; off >>= 1) v += __shfl_xor(v, off);
    return v;
}
__device__ __forceinline__ float wredmax(float v) {
    #pragma unroll
    for (int off = 32; off; off >>= 1) v = fmaxf(v, __shfl_xor(v, off));
    return v;
}

// ================= CSR build =================
__global__ __launch_bounds__(256) void k_hist(const int* __restrict__ ei, int* __restrict__ deg, int E_) {
    int e = blockIdx.x * 256 + threadIdx.x;
    if (e < E_) atomicAdd(&deg[ei[E_ + e]], 1);
}

__global__ __launch_bounds__(256) void k_scan1(const int* __restrict__ deg, int* __restrict__ bsum, int N_) {
    __shared__ int s[256];
    int i = blockIdx.x * 256 + threadIdx.x;
    s[threadIdx.x] = (i < N_) ? deg[i] : 0;
    __syncthreads();
    for (int off = 128; off; off >>= 1) {
        if (threadIdx.x < off) s[threadIdx.x] += s[threadIdx.x + off];
        __syncthreads();
    }
    if (threadIdx.x == 0) bsum[blockIdx.x] = s[0];
}

// parallel exclusive scan of block sums (single block, chunked w/ carry)
__global__ __launch_bounds__(512) void k_scan2(int* __restrict__ bsum, int nb) {
    __shared__ int s[512];
    __shared__ int carry_s;
    if (threadIdx.x == 0) carry_s = 0;
    __syncthreads();
    for (int base = 0; base < nb; base += 512) {
        int t = threadIdx.x;
        int idx = base + t;
        int v = (idx < nb) ? bsum[idx] : 0;
        s[t] = v;
        __syncthreads();
        #pragma unroll
        for (int off = 1; off < 512; off <<= 1) {
            int u = (t >= off) ? s[t - off] : 0;
            __syncthreads();
            s[t] += u;
            __syncthreads();
        }
        int carry = carry_s;
        if (idx < nb) bsum[idx] = carry + s[t] - v;   // exclusive
        __syncthreads();
        if (t == 0) carry_s = carry + s[511];
        __syncthreads();
    }
}

__global__ __launch_bounds__(256) void k_scan3(const int* __restrict__ deg, const int* __restrict__ bsum,
                                               int* __restrict__ row, int* __restrict__ cur, int N_, int E_) {
    __shared__ int s[256];
    int i = blockIdx.x * 256 + threadIdx.x;
    int d = (i < N_) ? deg[i] : 0;
    s[threadIdx.x] = d;
    __syncthreads();
    for (int off = 1; off < 256; off <<= 1) {
        int v = (threadIdx.x >= off) ? s[threadIdx.x - off] : 0;
        __syncthreads();
        s[threadIdx.x] += v;
        __syncthreads();
    }
    if (i < N_) {
        int ex = bsum[blockIdx.x] + s[threadIdx.x] - d;
        row[i] = ex; cur[i] = ex;
    }
    if (i == N_ - 1) row[N_] = E_;
}

__global__ __launch_bounds__(256) void k_scatter(const int* __restrict__ ei, int* __restrict__ cur,
                                                 int* __restrict__ csrc, int* __restrict__ ceid, int E_) {
    int e = blockIdx.x * 256 + threadIdx.x;
    if (e >= E_) return;
    int dst = ei[E_ + e];
    int slot = atomicAdd(&cur[dst], 1);
    csrc[slot] = ei[e];
    ceid[slot] = e;
}

__global__ __launch_bounds__(256) void k_gbounds(const int* __restrict__ batch, int* __restrict__ gst,
                                                 int N_, int G_) {
    int i = blockIdx.x * 256 + threadIdx.x;
    if (i >= N_) return;
    int b = batch[i];
    int prev = (i == 0) ? -1 : batch[i - 1];
    for (int g = prev + 1; g <= b; ++g) gst[g] = i;
    if (i == N_ - 1) { for (int g = b + 1; g <= G_; ++g) gst[g] = N_; }
}

// ---------- dual dense64: one raw-tile load, two matmuls, TWO LDS tiles ----------
// out1 = leaky(in @ w1^T + b1)  [stride 64]
// out2 =        in @ w2^T + b2  [stride 80, cols 0..63]
// dsout[r] = dot(out1_row_r, dva) (fused gate align dot)
// ti is reused as the out2 staging tile after the matmul (R7's third tile
// cost 50KB LDS -> 27% occupancy -> 165us; two tiles restore 4 blocks/CU).
__global__ __launch_bounds__(256) void k_dense64_dual(
    const float* __restrict__ in,
    const float* __restrict__ w1, const float* __restrict__ b1,
    const float* __restrict__ w2, const float* __restrict__ b2,
    float* __restrict__ out1, float* __restrict__ out2, int M,
    const float* __restrict__ dva, float* __restrict__ dsout)
{
    __shared__ float ti[64 * NPAD];   // input tile, then out2 tile
    __shared__ float t1[64 * NPAD];   // out1 tile
    int r0 = blockIdx.x * 64;
    for (int i = threadIdx.x; i < 4096; i += 256) {
        int r = i >> 6, c = i & 63; int gr = r0 + r;
        ti[r * NPAD + c] = (gr < M) ? in[(size_t)gr * 64 + c] : 0.f;
    }
    __syncthreads();
    int n = threadIdx.x & 63;
    int jl = __builtin_amdgcn_readfirstlane((threadIdx.x >> 6) << 4);
    float a1[16], a2[16];
    #pragma unroll
    for (int jj = 0; jj < 16; ++jj) { a1[jj] = b1[jl + jj]; a2[jj] = b2[jl + jj]; }
    for (int kc = 0; kc < 64; kc += 16) {
        float xr[16];
        #pragma unroll
        for (int i = 0; i < 16; ++i) xr[i] = ti[n * NPAD + kc + i];
        #pragma unroll
        for (int jj = 0; jj < 16; ++jj) {
            const float* wr1 = w1 + (jl + jj) * 64 + kc;
            const float* wr2 = w2 + (jl + jj) * 80 + kc;
            #pragma unroll
            for (int i = 0; i < 16; ++i) {
                a1[jj] = fmaf(wr1[i], xr[i], a1[jj]);
                a2[jj] = fmaf(wr2[i], xr[i], a2[jj]);
            }
        }
    }
    __syncthreads();          // all reads of ti done before reuse as out2 tile
    #pragma unroll
    for (int jj = 0; jj < 16; ++jj) {
        t1[n * NPAD + jl + jj] = leaky(a1[jj]);
        ti[n * NPAD + jl + jj] = a2[jj];
    }
    __syncthreads();
    for (int i = threadIdx.x; i < 4096; i += 256) {
        int r = i >> 6, c = i & 63; int gr = r0 + r;
        if (gr < M) {
            out1[(size_t)gr * 64 + c] = t1[r * NPAD + c];
            out2[(size_t)gr * 64 + c] = ti[r * NPAD + c];
        }
    }
    if (dsout != nullptr) {
        int wv = threadIdx.x >> 6;          // 0..3, rows wv*16..wv*16+15
        float wval = dva[n];
        #pragma unroll 4
        for (int q = 0; q < 16; ++q) {
            int r = (wv << 4) + q; int gr = r0 + r;
            float pv = wredsum(t1[r * NPAD + n] * wval);
            if (n == 0 && gr < M) dsout[gr] = pv;
        }
    }
}

// ---------- GATE layer: wave per dst node, 2-edge batch, double-buffered ----------
#define GDOT(acc, A0, A1, A2, A3) \
    acc = fmaf(A0.x, w2[0], acc);  acc = fmaf(A0.y, w2[1], acc);  \
    acc = fmaf(A0.z, w2[2], acc);  acc = fmaf(A0.w, w2[3], acc);  \
    acc = fmaf(A1.x, w2[4], acc);  acc = fmaf(A1.y, w2[5], acc);  \
    acc = fmaf(A1.z, w2[6], acc);  acc = fmaf(A1.w, w2[7], acc);  \
    acc = fmaf(A2.x, w2[8], acc);  acc = fmaf(A2.y, w2[9], acc);  \
    acc = fmaf(A2.z, w2[10], acc); acc = fmaf(A2.w, w2[11], acc); \
    acc = fmaf(A3.x, w2[12], acc); acc = fmaf(A3.y, w2[13], acc); \
    acc = fmaf(A3.z, w2[14], acc); acc = fmaf(A3.w, w2[15], acc);

__global__ __launch_bounds__(256, 4) void k_gate_gather(
    const float* __restrict__ u, const float* __restrict__ ea,
    const int* __restrict__ row, const int* __restrict__ csrc, const int* __restrict__ ceid,
    const float* __restrict__ wnl,
    const float* __restrict__ gaw, const float* __restrict__ gab,
    const float* __restrict__ sarr, float* __restrict__ Agg, int N_)
{
    int wid = (blockIdx.x * 256 + threadIdx.x) >> 6;
    int lane = threadIdx.x & 63;
    if (wid >= N_) return;
    float w2[16];
    #pragma unroll
    for (int k = 0; k < 16; ++k) w2[k] = wnl[lane * 80 + 64 + k];
    float g2 = gaw[64 + lane];
    float gb = gab[0];
    float sdst = sarr[wid];
    int beg = row[wid], end = row[wid + 1];
    float m = -INFINITY, d = 0.f, S = 0.f;
    for (int cs = beg; cs < end; cs += 64) {
        int cnt = min(64, end - cs);
        int src_l = 0, eid_l = 0;
        if (lane < cnt) { src_l = csrc[cs + lane]; eid_l = ceid[cs + lane]; }
        int cnt2 = (cnt + 1) & ~1;
        // prefetch batch 0 (edges 0,1); padded slot duplicates edge 0
        int j1 = (1 < cnt) ? 1 : 0;
        int s0 = bcasti(src_l, 0), s1 = bcasti(src_l, j1);
        int e0 = bcasti(eid_l, 0), e1 = bcasti(eid_l, j1);
        float u0 = u[(size_t)s0 * 64 + lane];
        float u1 = u[(size_t)s1 * 64 + lane];
        const float4* p0 = (const float4*)(ea + (size_t)e0 * 16);
        const float4* p1 = (const float4*)(ea + (size_t)e1 * 16);
        float4 a00 = p0[0], a01 = p0[1], a02 = p0[2], a03 = p0[3];
        float4 a10 = p1[0], a11 = p1[1], a12 = p1[2], a13 = p1[3];
        for (int l = 0; l < cnt2; l += 2) {
            // issue next batch's loads before current batch's compute chain
            int ln0 = (l + 2 < cnt) ? l + 2 : l;
            int ln1 = (l + 3 < cnt) ? l + 3 : l;
            int ns0 = bcasti(src_l, ln0), ns1 = bcasti(src_l, ln1);
            int ne0 = bcasti(eid_l, ln0), ne1 = bcasti(eid_l, ln1);
            float nu0 = u[(size_t)ns0 * 64 + lane];
            float nu1 = u[(size_t)ns1 * 64 + lane];
            const float4* q0 = (const float4*)(ea + (size_t)ne0 * 16);
            const float4* q1 = (const float4*)(ea + (size_t)ne1 * 16);
            float4 b00 = q0[0], b01 = q0[1], b02 = q0[2], b03 = q0[3];
            float4 b10 = q1[0], b11 = q1[1], b12 = q1[2], b13 = q1[3];
            // compute current batch
            float acc0 = u0, acc1 = u1;
            GDOT(acc0, a00, a01, a02, a03)
            GDOT(acc1, a10, a11, a12, a13)
            float xj0 = leaky(acc0), xj1 = leaky(acc1);
            float t0 = xj0 * g2, t1 = xj1 * g2;
            #pragma unroll
            for (int off = 32; off; off >>= 1) {
                t0 += __shfl_xor(t0, off);
                t1 += __shfl_xor(t1, off);
            }
            float sc0 = leaky(sdst + t0 + gb);
            float sc1 = (l + 1 < cnt) ? leaky(sdst + t1 + gb) : -INFINITY;
            float mn = fmaxf(m, fmaxf(sc0, sc1));
            float c = __expf(m - mn);
            float q0e = __expf(sc0 - mn), q1e = __expf(sc1 - mn);
            S = S * c;
            S = fmaf(q0e, xj0, S); S = fmaf(q1e, xj1, S);
            d = d * c + (q0e + q1e);
            m = mn;
            u0 = nu0; u1 = nu1;
            a00 = b00; a01 = b01; a02 = b02; a03 = b03;
            a10 = b10; a11 = b11; a12 = b12; a13 = b13;
        }
    }
    Agg[(size_t)wid * 64 + lane] = S / (d + 1e-16f);
}

// ---------- GAT layer: wave per dst node, pipelined weighted gather ----------
__global__ __launch_bounds__(256) void k_gat_gather(
    const int* __restrict__ row, const int* __restrict__ csrc,
    const float* __restrict__ x, const float* __restrict__ sarr,
    const float* __restrict__ tarr, const float* __restrict__ cb,
    float* __restrict__ Agg, int N_)
{
    int wid = (blockIdx.x * 256 + threadIdx.x) >> 6;
    int lane = threadIdx.x & 63;
    if (wid >= N_) return;
    float sdst = sarr[wid];
    float cbv = cb[0];
    int beg = row[wid], end = row[wid + 1];
    float m = -INFINITY, d = 0.f, S = 0.f;
    for (int cs = beg; cs < end; cs += 64) {
        int cnt = min(64, end - cs);
        int src_l = 0;
        if (lane < cnt) src_l = csrc[cs + lane];
        // issue first row-group loads before the score chain
        int s0 = bcasti(src_l, 0), s1 = bcasti(src_l, 1);
        int s2 = bcasti(src_l, 2), s3 = bcasti(src_l, 3);
        float r0 = x[(size_t)s0 * 64 + lane];
        float r1 = x[(size_t)s1 * 64 + lane];
        float r2 = x[(size_t)s2 * 64 + lane];
        float r3 = x[(size_t)s3 * 64 + lane];
        float sc_l = -INFINITY;
        if (lane < cnt) sc_l = leaky(sdst + tarr[src_l] + cbv);
        float cmax = wredmax(sc_l);
        float mn = fmaxf(m, cmax);
        float c = __expf(m - mn);
        float w_l = __expf(sc_l - mn);   // 0 for lanes >= cnt
        d = d * c + wredsum(w_l);
        S *= c;
        int cnt4 = (cnt + 3) & ~3;
        for (int l = 0; l < cnt4; l += 4) {
            int ln = (l + 4 < cnt4) ? l + 4 : 0;
            int t0 = bcasti(src_l, ln),     t1 = bcasti(src_l, ln + 1);
            int t2 = bcasti(src_l, ln + 2), t3 = bcasti(src_l, ln + 3);
            float p0 = x[(size_t)t0 * 64 + lane];
            float p1 = x[(size_t)t1 * 64 + lane];
            float p2 = x[(size_t)t2 * 64 + lane];
            float p3 = x[(size_t)t3 * 64 + lane];
            float w0 = bcastf(w_l, l),     w1 = bcastf(w_l, l + 1);
            float w2 = bcastf(w_l, l + 2), w3 = bcastf(w_l, l + 3);
            S = fmaf(w0, r0, S); S = fmaf(w1, r1, S);
            S = fmaf(w2, r2, S); S = fmaf(w3, r3, S);
            r0 = p0; r1 = p1; r2 = p2; r3 = p3;
        }
        m = mn;
    }
    Agg[(size_t)wid * 64 + lane] = S / (d + 1e-16f);
}

// ---------- fused node update: 128-row tile, 2 rows/lane (R4-proven) ----------
// mode 0: sout=dot(hv,dwa), tout=dot(hv,dwb)
// mode 1: sout=dot(0.5(hv+xold),dwa), tout=dot(hv,dwa)
// mode 2: sout=dot(hv,dwa)+dwb[0]
__global__ __launch_bounds__(512, 4) void k_node_update(
    const float* __restrict__ agg, const float* __restrict__ xold,
    const float* __restrict__ wa, const float* __restrict__ ba,
    const float* __restrict__ wih, const float* __restrict__ whh,
    const float* __restrict__ bih, const float* __restrict__ bhh,
    float* __restrict__ xout, int M,
    const float* __restrict__ dwa, const float* __restrict__ dwb,
    float* __restrict__ sout, float* __restrict__ tout, int mode)
{
    __shared__ float tA[128 * NPAD];   // agg tile, then h tile, then out tile
    __shared__ float tX[128 * NPAD];   // xold tile; head reused for dot partials
    int r0 = blockIdx.x * 128;
    for (int j = threadIdx.x; j < 2048; j += 512) {
        int r = j >> 4, c4 = (j & 15) << 2; int gr = r0 + r;
        float4 av = make_float4(0.f, 0.f, 0.f, 0.f), xv = av;
        if (gr < M) {
            av = *(const float4*)(agg  + (size_t)gr * 64 + c4);
            xv = *(const float4*)(xold + (size_t)gr * 64 + c4);
        }
        int b = r * NPAD + c4;
        tA[b] = av.x; tA[b + 1] = av.y; tA[b + 2] = av.z; tA[b + 3] = av.w;
        tX[b] = xv.x; tX[b + 1] = xv.y; tX[b + 2] = xv.z; tX[b + 3] = xv.w;
    }
    __syncthreads();
    int n = threadIdx.x & 63;
    int jl = __builtin_amdgcn_readfirstlane((threadIdx.x >> 6) << 3);  // 0..56

    // Phase B: h[jl..jl+8) = elu(Agg @ Wa^T + ba), rows n and n+64
    float hvA[8], hvB[8];
    {
        float accA[8], accB[8];
        #pragma unroll
        for (int jj = 0; jj < 8; ++jj) { float bv = ba[jl + jj]; accA[jj] = bv; accB[jj] = bv; }
        for (int kc = 0; kc < 64; kc += 16) {
            float aA[16], aB[16];
            #pragma unroll
            for (int i = 0; i < 16; ++i) {
                aA[i] = tA[n * NPAD + kc + i];
                aB[i] = tA[(n + 64) * NPAD + kc + i];
            }
            #pragma unroll
            for (int jj = 0; jj < 8; ++jj) {
                const float* wr = wa + (jl + jj) * 64 + kc;
                #pragma unroll
                for (int i = 0; i < 16; ++i) {
                    float wv = wr[i];
                    accA[jj] = fmaf(wv, aA[i], accA[jj]);
                    accB[jj] = fmaf(wv, aB[i], accB[jj]);
                }
            }
        }
        #pragma unroll
        for (int jj = 0; jj < 8; ++jj) { hvA[jj] = eluf(accA[jj]); hvB[jj] = eluf(accB[jj]); }
    }
    __syncthreads();          // all phase-B reads of tA done
    #pragma unroll
    for (int jj = 0; jj < 8; ++jj) {
        tA[n * NPAD + jl + jj] = hvA[jj];
        tA[(n + 64) * NPAD + jl + jj] = hvB[jj];
    }
    __syncthreads();          // h tile visible

    // Phase C: GRU. r/z accumulate input+hidden streams; 2 rows share weights.
    float rAc[8], rBc[8], zAc[8], zBc[8], nAc[8], nBc[8], hAc[8], hBc[8];
    #pragma unroll
    for (int jj = 0; jj < 8; ++jj) {
        float brz = bih[jl + jj] + bhh[jl + jj];
        float bz  = bih[64 + jl + jj] + bhh[64 + jl + jj];
        rAc[jj] = brz; rBc[jj] = brz;
        zAc[jj] = bz;  zBc[jj] = bz;
        nAc[jj] = bih[128 + jl + jj]; nBc[jj] = nAc[jj];
        hAc[jj] = bhh[128 + jl + jj]; hBc[jj] = hAc[jj];
    }
    for (int kc = 0; kc < 64; kc += 8) {
        float h0[8], h1[8], x0[8], x1[8];
        #pragma unroll
        for (int i = 0; i < 8; ++i) {
            h0[i] = tA[n * NPAD + kc + i];
            h1[i] = tA[(n + 64) * NPAD + kc + i];
            x0[i] = tX[n * NPAD + kc + i];
            x1[i] = tX[(n + 64) * NPAD + kc + i];
        }
        #pragma unroll
        for (int jj = 0; jj < 8; ++jj) {
            const float* w1 = wih + (jl + jj) * 64 + kc;          // r, input
            const float* w4 = whh + (jl + jj) * 64 + kc;          // r, hidden
            const float* w2 = wih + (64 + jl + jj) * 64 + kc;     // z, input
            const float* w5 = whh + (64 + jl + jj) * 64 + kc;     // z, hidden
            const float* w3 = wih + (128 + jl + jj) * 64 + kc;    // n, input
            const float* w6 = whh + (128 + jl + jj) * 64 + kc;    // n, hidden
            #pragma unroll
            for (int i = 0; i < 8; ++i) {
                float v1 = w1[i], v4 = w4[i], v2 = w2[i];
                float v5 = w5[i], v3 = w3[i], v6 = w6[i];
                rAc[jj] = fmaf(v1, h0[i], rAc[jj]); rAc[jj] = fmaf(v4, x0[i], rAc[jj]);
                rBc[jj] = fmaf(v1, h1[i], rBc[jj]); rBc[jj] = fmaf(v4, x1[i], rBc[jj]);
                zAc[jj] = fmaf(v2, h0[i], zAc[jj]); zAc[jj] = fmaf(v5, x0[i], zAc[jj]);
                zBc[jj] = fmaf(v2, h1[i], zBc[jj]); zBc[jj] = fmaf(v5, x1[i], zBc[jj]);
                nAc[jj] = fmaf(v3, h0[i], nAc[jj]); hAc[jj] = fmaf(v6, x0[i], hAc[jj]);
                nBc[jj] = fmaf(v3, h1[i], nBc[jj]); hBc[jj] = fmaf(v6, x1[i], hBc[jj]);
            }
        }
    }
    // final activation + (optional) fused dot partials, using in-register hv/xo
    float paA = 0.f, pbA = 0.f, paB = 0.f, pbB = 0.f;
    #pragma unroll
    for (int jj = 0; jj < 8; ++jj) {
        float r = sigm(rAc[jj]);
        float z = sigm(zAc[jj]);
        float nn = tanhfast(nAc[jj] + r * hAc[jj]);
        float xo = tX[n * NPAD + jl + jj];
        float v = (1.f - z) * nn + z * xo;
        hvA[jj] = fmaxf(v, 0.f);

        float rb = sigm(rBc[jj]);
        float zb = sigm(zBc[jj]);
        float nb_ = tanhfast(nBc[jj] + rb * hBc[jj]);
        float xob = tX[(n + 64) * NPAD + jl + jj];
        float vb = (1.f - zb) * nb_ + zb * xob;
        hvB[jj] = fmaxf(vb, 0.f);

        if (sout != nullptr) {
            float wav = dwa[jl + jj];
            float wbv = (mode == 0) ? dwb[jl + jj] : wav;
            float a1A = (mode == 1) ? 0.5f * (hvA[jj] + xo)  : hvA[jj];
            float a1B = (mode == 1) ? 0.5f * (hvB[jj] + xob) : hvB[jj];
            paA = fmaf(a1A, wav, paA); pbA = fmaf(hvA[jj], wbv, pbA);
            paB = fmaf(a1B, wav, paB); pbB = fmaf(hvB[jj], wbv, pbB);
        }
    }
    __syncthreads();          // all phase-C reads of tA/tX done
    #pragma unroll
    for (int jj = 0; jj < 8; ++jj) {
        tA[n * NPAD + jl + jj] = hvA[jj];
        tA[(n + 64) * NPAD + jl + jj] = hvB[jj];
    }
    if (sout != nullptr) {
        int w2i = (threadIdx.x >> 6) << 1;              // slot 0..14
        tX[n * 17 + w2i]            = paA;
        tX[n * 17 + w2i + 1]        = pbA;
        tX[(n + 64) * 17 + w2i]     = paB;
        tX[(n + 64) * 17 + w2i + 1] = pbB;
    }
    __syncthreads();
    for (int j = threadIdx.x; j < 2048; j += 512) {
        int r = j >> 4, c4 = (j & 15) << 2; int gr = r0 + r;
        if (gr < M) {
            int b = r * NPAD + c4;
            float4 ov = make_float4(tA[b], tA[b + 1], tA[b + 2], tA[b + 3]);
            *(float4*)(xout + (size_t)gr * 64 + c4) = ov;
        }
    }
    if (sout != nullptr && threadIdx.x < 128) {
        int r = threadIdx.x; int gr = r0 + r;
        if (gr < M) {
            float sa = 0.f, sb = 0.f;
            #pragma unroll
            for (int w = 0; w < 16; w += 2) { sa += tX[r * 17 + w]; sb += tX[r * 17 + w + 1]; }
            if (mode == 2) {
                sout[gr] = sa + dwb[0];
            } else {
                sout[gr] = sa; tout[gr] = sb;
            }
        }
    }
}

// ---------- readout: wave per graph, contiguous segment sum + relu ----------
__global__ __launch_bounds__(256) void k_seg_sum_relu(
    const float* __restrict__ x, const int* __restrict__ gst,
    float* __restrict__ outp, int G_)
{
    int g = (blockIdx.x * 256 + threadIdx.x) >> 6;
    int lane = threadIdx.x & 63;
    if (g >= G_) return;
    float S0 = 0.f, S1 = 0.f, S2 = 0.f, S3 = 0.f;
    int end = gst[g + 1];
    int i = gst[g];
    for (; i + 4 <= end; i += 4) {
        S0 += x[(size_t)i * 64 + lane];
        S1 += x[(size_t)(i + 1) * 64 + lane];
        S2 += x[(size_t)(i + 2) * 64 + lane];
        S3 += x[(size_t)(i + 3) * 64 + lane];
    }
    for (; i < end; ++i) S0 += x[(size_t)i * 64 + lane];
    outp[(size_t)g * 64 + lane] = fmaxf((S0 + S1) + (S2 + S3), 0.f);
}

// ---------- molecule attention: wave per graph, pipelined gather ----------
__global__ __launch_bounds__(256) void k_mol_gather(
    const float* __restrict__ xf, const float* __restrict__ cach,
    const float* __restrict__ stateIn, const int* __restrict__ gst,
    const float* __restrict__ dd,
    const float* __restrict__ maw, const float* __restrict__ mab,
    float* __restrict__ Agg, int G_)
{
    int g = (blockIdx.x * 256 + threadIdx.x) >> 6;
    int lane = threadIdx.x & 63;
    if (g >= G_) return;
    float o = stateIn[(size_t)g * 64 + lane];
    float og = wredsum(o * maw[lane]);
    float mb = mab[0];
    int beg = gst[g], end = gst[g + 1];
    float m = -INFINITY, d = 0.f, S = 0.f;
    for (int cs = beg; cs < end; cs += 64) {
        int cnt = min(64, end - cs);
        // issue first row-group loads before the score chain
        size_t rb = (size_t)cs * 64 + lane;
        float x0 = xf[rb],      c0 = cach[rb];
        float x1 = xf[rb + 64], c1 = cach[rb + 64];
        float x2 = xf[rb + 128], c2 = cach[rb + 128];
        float x3 = xf[rb + 192], c3 = cach[rb + 192];
        float sc_l = -INFINITY;
        if (lane < cnt) sc_l = leaky(og + dd[cs + lane] + mb);
        float cmax = wredmax(sc_l);
        float mn = fmaxf(m, cmax);
        float c = __expf(m - mn);
        float w_l = __expf(sc_l - mn);   // 0 for lanes >= cnt
        d = d * c + wredsum(w_l);
        S *= c;
        int cnt4 = (cnt + 3) & ~3;
        for (int l = 0; l < cnt4; l += 4) {
            int ln = (l + 4 < cnt4) ? l + 4 : 0;
            size_t rn = (size_t)(cs + ln) * 64 + lane;
            float y0 = xf[rn],       d0 = cach[rn];
            float y1 = xf[rn + 64],  d1 = cach[rn + 64];
            float y2 = xf[rn + 128], d2 = cach[rn + 128];
            float y3 = xf[rn + 192], d3 = cach[rn + 192];
            float w0 = bcastf(w_l, l),     w1 = bcastf(w_l, l + 1);
            float w2 = bcastf(w_l, l + 2), w3 = bcastf(w_l, l + 3);
            S = fmaf(w0, 0.5f * (x0 + c0), S);
            S = fmaf(w1, 0.5f * (x1 + c1), S);
            S = fmaf(w2, 0.5f * (x2 + c2), S);
            S = fmaf(w3, 0.5f * (x3 + c3), S);
            x0 = y0; c0 = d0; x1 = y1; c1 = d1;
            x2 = y2; c2 = d2; x3 = y3; c3 = d3;
        }
        m = mn;
    }
    Agg[(size_t)g * 64 + lane] = S / (d + 1e-16f);
}

// =====================================================================
extern "C" void kernel_launch(void* const* d_in, const int* in_sizes, int n_in,
                              void* d_out, int out_size, void* d_ws, size_t ws_size,
                              hipStream_t stream) {
    const float* raw           = (const float*)d_in[0];
    const int*   ei            = (const int*)d_in[1];
    const float* ea            = (const float*)d_in[2];
    const int*   batch         = (const int*)d_in[3];
    const float* lin1_w        = (const float*)d_in[4];
    const float* lin1_b        = (const float*)d_in[5];
    const float* gate_nl_w     = (const float*)d_in[6];
    const float* gate_nl_b     = (const float*)d_in[7];
    const float* gate_align_w  = (const float*)d_in[8];
    const float* gate_align_b  = (const float*)d_in[9];
    const float* gate_attend_w = (const float*)d_in[10];
    const float* gate_attend_b = (const float*)d_in[11];
    const float* conv_align_w  = (const float*)d_in[12];
    const float* conv_align_b  = (const float*)d_in[13];
    const float* conv_attend_w = (const float*)d_in[14];
    const float* conv_attend_b = (const float*)d_in[15];
    const float* gru_wih       = (const float*)d_in[16];
    const float* gru_whh       = (const float*)d_in[17];
    const float* gru_bih       = (const float*)d_in[18];
    const float* gru_bhh       = (const float*)d_in[19];
    const float* mol_align_w   = (const float*)d_in[20];
    const float* mol_align_b   = (const float*)d_in[21];
    const float* mol_attend_w  = (const float*)d_in[22];
    const float* mol_attend_b  = (const float*)d_in[23];
    const float* mol_wih       = (const float*)d_in[24];
    const float* mol_whh       = (const float*)d_in[25];
    const float* mol_bih       = (const float*)d_in[26];
    const float* mol_bhh       = (const float*)d_in[27];
    const float* lin2_w        = (const float*)d_in[28];
    const float* lin2_b        = (const float*)d_in[29];
    float* out = (float*)d_out;

    const int N = in_sizes[3];
    const int E = in_sizes[1] / 2;
    const int G = out_size;
    const size_t N64 = (size_t)N * 64;
    const size_t G64 = (size_t)G * 64;

    // ---- workspace layout ----
    float* f = (float*)d_ws;
    float* xA    = f;
    float* xB    = xA + N64;
    float* xD    = xB + N64;
    float* Agg   = xD + N64;
    float* u     = Agg + N64;
    float* sN    = u + N64;
    float* tN    = sN + N;
    float* dd    = tN + N;
    float* outS  = dd + N;
    float* outS2 = outS + G64;
    float* aggG  = outS2 + G64;
    int* row  = (int*)(aggG + G64);
    int* csrc = row + (N + 1);
    int* ceid = csrc + E;
    int* bsum = ceid + E;
    int* gst  = bsum + 512;
    int* deg = (int*)Agg;
    int* cur = deg + N;

    const int nb_node64  = (N + 63) / 64;
    const int nb_node128 = (N + 127) / 128;
    const int nb_edge   = (E + 255) / 256;
    const int nb_nodes  = (N + 255) / 256;
    const int nb_waveN  = (N + 3) / 4;
    const int nb_waveG  = (G + 3) / 4;
    const int nb_nodeG  = (G + 127) / 128;

    // ---- CSR build ----
    hipMemsetAsync(deg, 0, (size_t)N * 4, stream);
    k_hist<<<nb_edge, 256, 0, stream>>>(ei, deg, E);
    k_scan1<<<nb_nodes, 256, 0, stream>>>(deg, bsum, N);
    k_scan2<<<1, 512, 0, stream>>>(bsum, nb_nodes);
    k_scan3<<<nb_nodes, 256, 0, stream>>>(deg, bsum, row, cur, N, E);
    k_scatter<<<nb_edge, 256, 0, stream>>>(ei, cur, csrc, ceid, E);
    k_gbounds<<<nb_nodes, 256, 0, stream>>>(batch, gst, N, G);

    // ---- lin1 + gate node-part in ONE pass (+fused gate align dot -> sN) ----
    k_dense64_dual<<<nb_node64, 256, 0, stream>>>(raw, lin1_w, lin1_b,
                                                  gate_nl_w, gate_nl_b,
                                                  xA, u, N, gate_align_w, sN);

    // ---- layer 0: GATEConv (xA -> xB); emits align dots for GAT layer 0 ----
    k_gate_gather<<<nb_waveN, 256, 0, stream>>>(u, ea, row, csrc, ceid,
                                                gate_nl_w, gate_align_w, gate_align_b,
                                                sN, Agg, N);
    k_node_update<<<nb_node128, 512, 0, stream>>>(Agg, xA, gate_attend_w, gate_attend_b,
                                                  gru_wih, gru_whh, gru_bih, gru_bhh, xB, N,
                                                  conv_align_w, conv_align_w + 64, sN, tN, 0);

    // ---- GAT layer 0 (xB -> xD); emits align dots for GAT layer 1 ----
    k_gat_gather<<<nb_waveN, 256, 0, stream>>>(row, csrc, xB, sN, tN, conv_align_b, Agg, N);
    k_node_update<<<nb_node128, 512, 0, stream>>>(Agg, xB, conv_attend_w, conv_attend_b,
                                                  gru_wih + 12288, gru_whh + 12288,
                                                  gru_bih + 192, gru_bhh + 192, xD, N,
                                                  conv_align_w + 128, conv_align_w + 192, sN, tN, 0);

    // ---- GAT layer 1 (xD -> xA); emits mol dots dd0 -> dd, dd1 -> tN ----
    k_gat_gather<<<nb_waveN, 256, 0, stream>>>(row, csrc, xD, sN, tN, conv_align_b + 1, Agg, N);
    k_node_update<<<nb_node128, 512, 0, stream>>>(Agg, xD, conv_attend_w + 4096, conv_attend_b + 64,
                                                  gru_wih + 24576, gru_whh + 24576,
                                                  gru_bih + 384, gru_bhh + 384, xA, N,
                                                  mol_align_w + 64, mol_align_w + 64, dd, tN, 1);

    // ---- molecule readout ----
    k_seg_sum_relu<<<nb_waveG, 256, 0, stream>>>(xA, gst, outS, G);

    // t=0: cached = xD, dots = dd (0.5(xA+xD).maw2)
    k_mol_gather<<<nb_waveG, 256, 0, stream>>>(xA, xD, outS, gst, dd,
                                               mol_align_w, mol_align_b, aggG, G);
    k_node_update<<<nb_nodeG, 512, 0, stream>>>(aggG, outS, mol_attend_w, mol_attend_b,
                                                mol_wih, mol_whh, mol_bih, mol_bhh, outS2, G,
                                                nullptr, nullptr, nullptr, nullptr, 0);
    // t=1: cached = xA, dots = tN (xA.maw2); fused lin2 -> out
    k_mol_gather<<<nb_waveG, 256, 0, stream>>>(xA, xA, outS2, gst, tN,
                                               mol_align_w, mol_align_b, aggG, G);
    k_node_update<<<nb_nodeG, 512, 0, stream>>>(aggG, outS2, mol_attend_w, mol_attend_b,
                                                mol_wih, mol_whh, mol_bih, mol_bhh, outS, G,
                                                lin2_w, lin2_b, out, nullptr, 2);
}

// Round 13
// 1083.879 us; speedup vs baseline: 1.0418x; 1.0053x over previous
//
#include <hip/hip_runtime.h>
#include <math.h>

#define NPAD 65

// ---------- small device helpers ----------
__device__ __forceinline__ float leaky(float x) { return x > 0.f ? x : 0.01f * x; }
__device__ __forceinline__ float eluf(float x)  { return x > 0.f ? x : (__expf(x) - 1.f); }
__device__ __forceinline__ float sigm(float x)  { return 1.f / (1.f + __expf(-x)); }
__device__ __forceinline__ float tanhfast(float x) { return 1.f - 2.f / (__expf(2.f * x) + 1.f); }

__device__ __forceinline__ float bcastf(float v, int k) {
    return __uint_as_float((unsigned)__builtin_amdgcn_readlane((int)__float_as_uint(v), k));
}
__device__ __forceinline__ int bcasti(int v, int k) {
    return __builtin_amdgcn_readlane(v, k);
}
__device__ __forceinline__ float wredsum(float v) {
    #pragma unroll
    for (int off = 32; off; off >>= 1) v += __shfl_xor(v, off);
    return v;
}
__device__ __forceinline__ float wredmax(float v) {
    #pragma unroll
    for (int off = 32; off; off >>= 1) v = fmaxf(v, __shfl_xor(v, off));
    return v;
}

// ================= CSR build =================
__global__ __launch_bounds__(256) void k_hist(const int* __restrict__ ei, int* __restrict__ deg, int E_) {
    int e = blockIdx.x * 256 + threadIdx.x;
    if (e < E_) atomicAdd(&deg[ei[E_ + e]], 1);
}

__global__ __launch_bounds__(256) void k_scan1(const int* __restrict__ deg, int* __restrict__ bsum, int N_) {
    __shared__ int s[256];
    int i = blockIdx.x * 256 + threadIdx.x;
    s[threadIdx.x] = (i < N_) ? deg[i] : 0;
    __syncthreads();
    for (int off = 128; off; off >>= 1) {
        if (threadIdx.x < off) s[threadIdx.x] += s[threadIdx.x + off];
        __syncthreads();
    }
    if (threadIdx.x == 0) bsum[blockIdx.x] = s[0];
}

// parallel exclusive scan of block sums (single block, chunked w/ carry)
__global__ __launch_bounds__(512) void k_scan2(int* __restrict__ bsum, int nb) {
    __shared__ int s[512];
    __shared__ int carry_s;
    if (threadIdx.x == 0) carry_s = 0;
    __syncthreads();
    for (int base = 0; base < nb; base += 512) {
        int t = threadIdx.x;
        int idx = base + t;
        int v = (idx < nb) ? bsum[idx] : 0;
        s[t] = v;
        __syncthreads();
        #pragma unroll
        for (int off = 1; off < 512; off <<= 1) {
            int u = (t >= off) ? s[t - off] : 0;
            __syncthreads();
            s[t] += u;
            __syncthreads();
        }
        int carry = carry_s;
        if (idx < nb) bsum[idx] = carry + s[t] - v;   // exclusive
        __syncthreads();
        if (t == 0) carry_s = carry + s[511];
        __syncthreads();
    }
}

__global__ __launch_bounds__(256) void k_scan3(const int* __restrict__ deg, const int* __restrict__ bsum,
                                               int* __restrict__ row, int* __restrict__ cur, int N_, int E_) {
    __shared__ int s[256];
    int i = blockIdx.x * 256 + threadIdx.x;
    int d = (i < N_) ? deg[i] : 0;
    s[threadIdx.x] = d;
    __syncthreads();
    for (int off = 1; off < 256; off <<= 1) {
        int v = (threadIdx.x >= off) ? s[threadIdx.x - off] : 0;
        __syncthreads();
        s[threadIdx.x] += v;
        __syncthreads();
    }
    if (i < N_) {
        int ex = bsum[blockIdx.x] + s[threadIdx.x] - d;
        row[i] = ex; cur[i] = ex;
    }
    if (i == N_ - 1) row[N_] = E_;
}

__global__ __launch_bounds__(256) void k_scatter(const int* __restrict__ ei, int* __restrict__ cur,
                                                 int* __restrict__ csrc, int* __restrict__ ceid, int E_) {
    int e = blockIdx.x * 256 + threadIdx.x;
    if (e >= E_) return;
    int dst = ei[E_ + e];
    int slot = atomicAdd(&cur[dst], 1);
    csrc[slot] = ei[e];
    ceid[slot] = e;
}

__global__ __launch_bounds__(256) void k_gbounds(const int* __restrict__ batch, int* __restrict__ gst,
                                                 int N_, int G_) {
    int i = blockIdx.x * 256 + threadIdx.x;
    if (i >= N_) return;
    int b = batch[i];
    int prev = (i == 0) ? -1 : batch[i - 1];
    for (int g = prev + 1; g <= b; ++g) gst[g] = i;
    if (i == N_ - 1) { for (int g = b + 1; g <= G_; ++g) gst[g] = N_; }
}

// ---------- dual dense64: one raw-tile load, two matmuls, TWO LDS tiles ----------
__global__ __launch_bounds__(256) void k_dense64_dual(
    const float* __restrict__ in,
    const float* __restrict__ w1, const float* __restrict__ b1,
    const float* __restrict__ w2, const float* __restrict__ b2,
    float* __restrict__ out1, float* __restrict__ out2, int M,
    const float* __restrict__ dva, float* __restrict__ dsout)
{
    __shared__ float ti[64 * NPAD];   // input tile, then out2 tile
    __shared__ float t1[64 * NPAD];   // out1 tile
    int r0 = blockIdx.x * 64;
    for (int i = threadIdx.x; i < 4096; i += 256) {
        int r = i >> 6, c = i & 63; int gr = r0 + r;
        ti[r * NPAD + c] = (gr < M) ? in[(size_t)gr * 64 + c] : 0.f;
    }
    __syncthreads();
    int n = threadIdx.x & 63;
    int jl = __builtin_amdgcn_readfirstlane((threadIdx.x >> 6) << 4);
    float a1[16], a2[16];
    #pragma unroll
    for (int jj = 0; jj < 16; ++jj) { a1[jj] = b1[jl + jj]; a2[jj] = b2[jl + jj]; }
    for (int kc = 0; kc < 64; kc += 16) {
        float xr[16];
        #pragma unroll
        for (int i = 0; i < 16; ++i) xr[i] = ti[n * NPAD + kc + i];
        #pragma unroll
        for (int jj = 0; jj < 16; ++jj) {
            const float* wr1 = w1 + (jl + jj) * 64 + kc;
            const float* wr2 = w2 + (jl + jj) * 80 + kc;
            #pragma unroll
            for (int i = 0; i < 16; ++i) {
                a1[jj] = fmaf(wr1[i], xr[i], a1[jj]);
                a2[jj] = fmaf(wr2[i], xr[i], a2[jj]);
            }
        }
    }
    __syncthreads();          // all reads of ti done before reuse as out2 tile
    #pragma unroll
    for (int jj = 0; jj < 16; ++jj) {
        t1[n * NPAD + jl + jj] = leaky(a1[jj]);
        ti[n * NPAD + jl + jj] = a2[jj];
    }
    __syncthreads();
    for (int i = threadIdx.x; i < 4096; i += 256) {
        int r = i >> 6, c = i & 63; int gr = r0 + r;
        if (gr < M) {
            out1[(size_t)gr * 64 + c] = t1[r * NPAD + c];
            out2[(size_t)gr * 64 + c] = ti[r * NPAD + c];
        }
    }
    if (dsout != nullptr) {
        int wv = threadIdx.x >> 6;          // 0..3, rows wv*16..wv*16+15
        float wval = dva[n];
        #pragma unroll 4
        for (int q = 0; q < 16; ++q) {
            int r = (wv << 4) + q; int gr = r0 + r;
            float pv = wredsum(t1[r * NPAD + n] * wval);
            if (n == 0 && gr < M) dsout[gr] = pv;
        }
    }
}

// ---------- GATE layer: wave per dst node, 2-edge batch, double-buffered ----------
#define GDOT(acc, A0, A1, A2, A3) \
    acc = fmaf(A0.x, w2[0], acc);  acc = fmaf(A0.y, w2[1], acc);  \
    acc = fmaf(A0.z, w2[2], acc);  acc = fmaf(A0.w, w2[3], acc);  \
    acc = fmaf(A1.x, w2[4], acc);  acc = fmaf(A1.y, w2[5], acc);  \
    acc = fmaf(A1.z, w2[6], acc);  acc = fmaf(A1.w, w2[7], acc);  \
    acc = fmaf(A2.x, w2[8], acc);  acc = fmaf(A2.y, w2[9], acc);  \
    acc = fmaf(A2.z, w2[10], acc); acc = fmaf(A2.w, w2[11], acc); \
    acc = fmaf(A3.x, w2[12], acc); acc = fmaf(A3.y, w2[13], acc); \
    acc = fmaf(A3.z, w2[14], acc); acc = fmaf(A3.w, w2[15], acc);

__global__ __launch_bounds__(256, 4) void k_gate_gather(
    const float* __restrict__ u, const float* __restrict__ ea,
    const int* __restrict__ row, const int* __restrict__ csrc, const int* __restrict__ ceid,
    const float* __restrict__ wnl,
    const float* __restrict__ gaw, const float* __restrict__ gab,
    const float* __restrict__ sarr, float* __restrict__ Agg, int N_)
{
    int wid = (blockIdx.x * 256 + threadIdx.x) >> 6;
    int lane = threadIdx.x & 63;
    if (wid >= N_) return;
    float w2[16];
    #pragma unroll
    for (int k = 0; k < 16; ++k) w2[k] = wnl[lane * 80 + 64 + k];
    float g2 = gaw[64 + lane];
    float gb = gab[0];
    float sdst = sarr[wid];
    int beg = row[wid], end = row[wid + 1];
    float m = -INFINITY, d = 0.f, S = 0.f;
    for (int cs = beg; cs < end; cs += 64) {
        int cnt = min(64, end - cs);
        int src_l = 0, eid_l = 0;
        if (lane < cnt) { src_l = csrc[cs + lane]; eid_l = ceid[cs + lane]; }
        int cnt2 = (cnt + 1) & ~1;
        // prefetch batch 0 (edges 0,1); padded slot duplicates edge 0
        int j1 = (1 < cnt) ? 1 : 0;
        int s0 = bcasti(src_l, 0), s1 = bcasti(src_l, j1);
        int e0 = bcasti(eid_l, 0), e1 = bcasti(eid_l, j1);
        float u0 = u[(size_t)s0 * 64 + lane];
        float u1 = u[(size_t)s1 * 64 + lane];
        const float4* p0 = (const float4*)(ea + (size_t)e0 * 16);
        const float4* p1 = (const float4*)(ea + (size_t)e1 * 16);
        float4 a00 = p0[0], a01 = p0[1], a02 = p0[2], a03 = p0[3];
        float4 a10 = p1[0], a11 = p1[1], a12 = p1[2], a13 = p1[3];
        for (int l = 0; l < cnt2; l += 2) {
            // issue next batch's loads before current batch's compute chain
            int ln0 = (l + 2 < cnt) ? l + 2 : l;
            int ln1 = (l + 3 < cnt) ? l + 3 : l;
            int ns0 = bcasti(src_l, ln0), ns1 = bcasti(src_l, ln1);
            int ne0 = bcasti(eid_l, ln0), ne1 = bcasti(eid_l, ln1);
            float nu0 = u[(size_t)ns0 * 64 + lane];
            float nu1 = u[(size_t)ns1 * 64 + lane];
            const float4* q0 = (const float4*)(ea + (size_t)ne0 * 16);
            const float4* q1 = (const float4*)(ea + (size_t)ne1 * 16);
            float4 b00 = q0[0], b01 = q0[1], b02 = q0[2], b03 = q0[3];
            float4 b10 = q1[0], b11 = q1[1], b12 = q1[2], b13 = q1[3];
            // compute current batch
            float acc0 = u0, acc1 = u1;
            GDOT(acc0, a00, a01, a02, a03)
            GDOT(acc1, a10, a11, a12, a13)
            float xj0 = leaky(acc0), xj1 = leaky(acc1);
            float t0 = xj0 * g2, t1 = xj1 * g2;
            #pragma unroll
            for (int off = 32; off; off >>= 1) {
                t0 += __shfl_xor(t0, off);
                t1 += __shfl_xor(t1, off);
            }
            float sc0 = leaky(sdst + t0 + gb);
            float sc1 = (l + 1 < cnt) ? leaky(sdst + t1 + gb) : -INFINITY;
            float mn = fmaxf(m, fmaxf(sc0, sc1));
            float c = __expf(m - mn);
            float q0e = __expf(sc0 - mn), q1e = __expf(sc1 - mn);
            S = S * c;
            S = fmaf(q0e, xj0, S); S = fmaf(q1e, xj1, S);
            d = d * c + (q0e + q1e);
            m = mn;
            u0 = nu0; u1 = nu1;
            a00 = b00; a01 = b01; a02 = b02; a03 = b03;
            a10 = b10; a11 = b11; a12 = b12; a13 = b13;
        }
    }
    Agg[(size_t)wid * 64 + lane] = S / (d + 1e-16f);
}

// ---------- GAT layer: wave per 2 dst nodes, interleaved independent chains ----------
// Two nodes' score phases + weighted-sum streams run in straight-line code:
// doubles per-wave memory-level parallelism on the random row gathers.
// m init = -FLT_MAX (not -INF) so exhausted/empty chunks are exact no-ops
// (c=exp(0)=1, w=exp(-INF)=0) with no NaN hazard. 4-way split accumulators
// break the serial S fmaf chain.
__global__ __launch_bounds__(256) void k_gat_gather(
    const int* __restrict__ row, const int* __restrict__ csrc,
    const float* __restrict__ x, const float* __restrict__ sarr,
    const float* __restrict__ tarr, const float* __restrict__ cb,
    float* __restrict__ Agg, int N_)
{
    int w = (blockIdx.x * 256 + threadIdx.x) >> 6;   // pair id
    int lane = threadIdx.x & 63;
    int idA = w * 2, idB = w * 2 + 1;
    if (idA >= N_) return;
    float cbv = cb[0];
    float sdA = sarr[idA];
    int begA = row[idA], endA = row[idA + 1];
    int begB = 0, endB = 0; float sdB = 0.f;
    if (idB < N_) { sdB = sarr[idB]; begB = row[idB]; endB = row[idB + 1]; }
    float mA = -3.4e38f, dA = 0.f, SA0 = 0.f, SA1 = 0.f, SA2 = 0.f, SA3 = 0.f;
    float mB = -3.4e38f, dB = 0.f, SB0 = 0.f, SB1 = 0.f, SB2 = 0.f, SB3 = 0.f;
    int nchA = (endA - begA + 63) >> 6;
    int nchB = (endB - begB + 63) >> 6;
    int nch = max(nchA, nchB);
    for (int ch = 0; ch < nch; ++ch) {
        int csA = begA + (ch << 6), csB = begB + (ch << 6);
        int cntA = (ch < nchA) ? min(64, endA - csA) : 0;
        int cntB = (ch < nchB) ? min(64, endB - csB) : 0;
        int srcA = 0, srcB = 0;
        if (lane < cntA) srcA = csrc[csA + lane];
        if (lane < cntB) srcB = csrc[csB + lane];
        // two independent score chains (loads interleave)
        float scA = -INFINITY, scB = -INFINITY;
        if (lane < cntA) scA = leaky(sdA + tarr[srcA] + cbv);
        if (lane < cntB) scB = leaky(sdB + tarr[srcB] + cbv);
        float cmA = scA, cmB = scB;
        #pragma unroll
        for (int off = 32; off; off >>= 1) {
            cmA = fmaxf(cmA, __shfl_xor(cmA, off));
            cmB = fmaxf(cmB, __shfl_xor(cmB, off));
        }
        float mnA = fmaxf(mA, cmA), mnB = fmaxf(mB, cmB);
        float cA = __expf(mA - mnA), cB = __expf(mB - mnB);
        float wA = __expf(scA - mnA), wB = __expf(scB - mnB);  // 0 beyond cnt
        float sA = wA, sB = wB;
        #pragma unroll
        for (int off = 32; off; off >>= 1) {
            sA += __shfl_xor(sA, off);
            sB += __shfl_xor(sB, off);
        }
        dA = dA * cA + sA; dB = dB * cB + sB;
        SA0 *= cA; SA1 *= cA; SA2 *= cA; SA3 *= cA;
        SB0 *= cB; SB1 *= cB; SB2 *= cB; SB3 *= cB;
        mA = mnA; mB = mnB;
        // joint weighted-sum: 8 row loads per group, one group prefetched ahead;
        // beyond a node's cnt4 the weights are 0 (harmless row-0 loads).
        int cnt4A = (cntA + 3) & ~3, cnt4B = (cntB + 3) & ~3;
        int cnt4 = max(cnt4A, cnt4B);
        int a0 = bcasti(srcA, 0), a1 = bcasti(srcA, 1);
        int a2 = bcasti(srcA, 2), a3 = bcasti(srcA, 3);
        int b0 = bcasti(srcB, 0), b1 = bcasti(srcB, 1);
        int b2 = bcasti(srcB, 2), b3 = bcasti(srcB, 3);
        float rA0 = x[(size_t)a0 * 64 + lane], rA1 = x[(size_t)a1 * 64 + lane];
        float rA2 = x[(size_t)a2 * 64 + lane], rA3 = x[(size_t)a3 * 64 + lane];
        float rB0 = x[(size_t)b0 * 64 + lane], rB1 = x[(size_t)b1 * 64 + lane];
        float rB2 = x[(size_t)b2 * 64 + lane], rB3 = x[(size_t)b3 * 64 + lane];
        for (int l = 0; l < cnt4; l += 4) {
            int ln = (l + 4 < cnt4) ? l + 4 : 0;
            int na0 = bcasti(srcA, ln),     na1 = bcasti(srcA, ln + 1);
            int na2 = bcasti(srcA, ln + 2), na3 = bcasti(srcA, ln + 3);
            int nb0 = bcasti(srcB, ln),     nb1 = bcasti(srcB, ln + 1);
            int nb2 = bcasti(srcB, ln + 2), nb3 = bcasti(srcB, ln + 3);
            float pA0 = x[(size_t)na0 * 64 + lane], pA1 = x[(size_t)na1 * 64 + lane];
            float pA2 = x[(size_t)na2 * 64 + lane], pA3 = x[(size_t)na3 * 64 + lane];
            float pB0 = x[(size_t)nb0 * 64 + lane], pB1 = x[(size_t)nb1 * 64 + lane];
            float pB2 = x[(size_t)nb2 * 64 + lane], pB3 = x[(size_t)nb3 * 64 + lane];
            float wA0 = bcastf(wA, l),     wA1 = bcastf(wA, l + 1);
            float wA2 = bcastf(wA, l + 2), wA3 = bcastf(wA, l + 3);
            float wB0 = bcastf(wB, l),     wB1 = bcastf(wB, l + 1);
            float wB2 = bcastf(wB, l + 2), wB3 = bcastf(wB, l + 3);
            SA0 = fmaf(wA0, rA0, SA0); SA1 = fmaf(wA1, rA1, SA1);
            SA2 = fmaf(wA2, rA2, SA2); SA3 = fmaf(wA3, rA3, SA3);
            SB0 = fmaf(wB0, rB0, SB0); SB1 = fmaf(wB1, rB1, SB1);
            SB2 = fmaf(wB2, rB2, SB2); SB3 = fmaf(wB3, rB3, SB3);
            rA0 = pA0; rA1 = pA1; rA2 = pA2; rA3 = pA3;
            rB0 = pB0; rB1 = pB1; rB2 = pB2; rB3 = pB3;
        }
    }
    float SAt = (SA0 + SA1) + (SA2 + SA3);
    Agg[(size_t)idA * 64 + lane] = SAt / (dA + 1e-16f);
    if (idB < N_) {
        float SBt = (SB0 + SB1) + (SB2 + SB3);
        Agg[(size_t)idB * 64 + lane] = SBt / (dB + 1e-16f);
    }
}

// ---------- fused node update: 128-row tile, 2 rows/lane (R4-proven) ----------
// mode 0: sout=dot(hv,dwa), tout=dot(hv,dwb)
// mode 1: sout=dot(0.5(hv+xold),dwa), tout=dot(hv,dwa)
// mode 2: sout=dot(hv,dwa)+dwb[0]
__global__ __launch_bounds__(512, 4) void k_node_update(
    const float* __restrict__ agg, const float* __restrict__ xold,
    const float* __restrict__ wa, const float* __restrict__ ba,
    const float* __restrict__ wih, const float* __restrict__ whh,
    const float* __restrict__ bih, const float* __restrict__ bhh,
    float* __restrict__ xout, int M,
    const float* __restrict__ dwa, const float* __restrict__ dwb,
    float* __restrict__ sout, float* __restrict__ tout, int mode)
{
    __shared__ float tA[128 * NPAD];   // agg tile, then h tile, then out tile
    __shared__ float tX[128 * NPAD];   // xold tile; head reused for dot partials
    int r0 = blockIdx.x * 128;
    for (int j = threadIdx.x; j < 2048; j += 512) {
        int r = j >> 4, c4 = (j & 15) << 2; int gr = r0 + r;
        float4 av = make_float4(0.f, 0.f, 0.f, 0.f), xv = av;
        if (gr < M) {
            av = *(const float4*)(agg  + (size_t)gr * 64 + c4);
            xv = *(const float4*)(xold + (size_t)gr * 64 + c4);
        }
        int b = r * NPAD + c4;
        tA[b] = av.x; tA[b + 1] = av.y; tA[b + 2] = av.z; tA[b + 3] = av.w;
        tX[b] = xv.x; tX[b + 1] = xv.y; tX[b + 2] = xv.z; tX[b + 3] = xv.w;
    }
    __syncthreads();
    int n = threadIdx.x & 63;
    int jl = __builtin_amdgcn_readfirstlane((threadIdx.x >> 6) << 3);  // 0..56

    // Phase B: h[jl..jl+8) = elu(Agg @ Wa^T + ba), rows n and n+64
    float hvA[8], hvB[8];
    {
        float accA[8], accB[8];
        #pragma unroll
        for (int jj = 0; jj < 8; ++jj) { float bv = ba[jl + jj]; accA[jj] = bv; accB[jj] = bv; }
        for (int kc = 0; kc < 64; kc += 16) {
            float aA[16], aB[16];
            #pragma unroll
            for (int i = 0; i < 16; ++i) {
                aA[i] = tA[n * NPAD + kc + i];
                aB[i] = tA[(n + 64) * NPAD + kc + i];
            }
            #pragma unroll
            for (int jj = 0; jj < 8; ++jj) {
                const float* wr = wa + (jl + jj) * 64 + kc;
                #pragma unroll
                for (int i = 0; i < 16; ++i) {
                    float wv = wr[i];
                    accA[jj] = fmaf(wv, aA[i], accA[jj]);
                    accB[jj] = fmaf(wv, aB[i], accB[jj]);
                }
            }
        }
        #pragma unroll
        for (int jj = 0; jj < 8; ++jj) { hvA[jj] = eluf(accA[jj]); hvB[jj] = eluf(accB[jj]); }
    }
    __syncthreads();          // all phase-B reads of tA done
    #pragma unroll
    for (int jj = 0; jj < 8; ++jj) {
        tA[n * NPAD + jl + jj] = hvA[jj];
        tA[(n + 64) * NPAD + jl + jj] = hvB[jj];
    }
    __syncthreads();          // h tile visible

    // Phase C: GRU. r/z accumulate input+hidden streams; 2 rows share weights.
    float rAc[8], rBc[8], zAc[8], zBc[8], nAc[8], nBc[8], hAc[8], hBc[8];
    #pragma unroll
    for (int jj = 0; jj < 8; ++jj) {
        float brz = bih[jl + jj] + bhh[jl + jj];
        float bz  = bih[64 + jl + jj] + bhh[64 + jl + jj];
        rAc[jj] = brz; rBc[jj] = brz;
        zAc[jj] = bz;  zBc[jj] = bz;
        nAc[jj] = bih[128 + jl + jj]; nBc[jj] = nAc[jj];
        hAc[jj] = bhh[128 + jl + jj]; hBc[jj] = hAc[jj];
    }
    for (int kc = 0; kc < 64; kc += 8) {
        float h0[8], h1[8], x0[8], x1[8];
        #pragma unroll
        for (int i = 0; i < 8; ++i) {
            h0[i] = tA[n * NPAD + kc + i];
            h1[i] = tA[(n + 64) * NPAD + kc + i];
            x0[i] = tX[n * NPAD + kc + i];
            x1[i] = tX[(n + 64) * NPAD + kc + i];
        }
        #pragma unroll
        for (int jj = 0; jj < 8; ++jj) {
            const float* w1 = wih + (jl + jj) * 64 + kc;          // r, input
            const float* w4 = whh + (jl + jj) * 64 + kc;          // r, hidden
            const float* w2 = wih + (64 + jl + jj) * 64 + kc;     // z, input
            const float* w5 = whh + (64 + jl + jj) * 64 + kc;     // z, hidden
            const float* w3 = wih + (128 + jl + jj) * 64 + kc;    // n, input
            const float* w6 = whh + (128 + jl + jj) * 64 + kc;    // n, hidden
            #pragma unroll
            for (int i = 0; i < 8; ++i) {
                float v1 = w1[i], v4 = w4[i], v2 = w2[i];
                float v5 = w5[i], v3 = w3[i], v6 = w6[i];
                rAc[jj] = fmaf(v1, h0[i], rAc[jj]); rAc[jj] = fmaf(v4, x0[i], rAc[jj]);
                rBc[jj] = fmaf(v1, h1[i], rBc[jj]); rBc[jj] = fmaf(v4, x1[i], rBc[jj]);
                zAc[jj] = fmaf(v2, h0[i], zAc[jj]); zAc[jj] = fmaf(v5, x0[i], zAc[jj]);
                zBc[jj] = fmaf(v2, h1[i], zBc[jj]); zBc[jj] = fmaf(v5, x1[i], zBc[jj]);
                nAc[jj] = fmaf(v3, h0[i], nAc[jj]); hAc[jj] = fmaf(v6, x0[i], hAc[jj]);
                nBc[jj] = fmaf(v3, h1[i], nBc[jj]); hBc[jj] = fmaf(v6, x1[i], hBc[jj]);
            }
        }
    }
    // final activation + (optional) fused dot partials, using in-register hv/xo
    float paA = 0.f, pbA = 0.f, paB = 0.f, pbB = 0.f;
    #pragma unroll
    for (int jj = 0; jj < 8; ++jj) {
        float r = sigm(rAc[jj]);
        float z = sigm(zAc[jj]);
        float nn = tanhfast(nAc[jj] + r * hAc[jj]);
        float xo = tX[n * NPAD + jl + jj];
        float v = (1.f - z) * nn + z * xo;
        hvA[jj] = fmaxf(v, 0.f);

        float rb = sigm(rBc[jj]);
        float zb = sigm(zBc[jj]);
        float nb_ = tanhfast(nBc[jj] + rb * hBc[jj]);
        float xob = tX[(n + 64) * NPAD + jl + jj];
        float vb = (1.f - zb) * nb_ + zb * xob;
        hvB[jj] = fmaxf(vb, 0.f);

        if (sout != nullptr) {
            float wav = dwa[jl + jj];
            float wbv = (mode == 0) ? dwb[jl + jj] : wav;
            float a1A = (mode == 1) ? 0.5f * (hvA[jj] + xo)  : hvA[jj];
            float a1B = (mode == 1) ? 0.5f * (hvB[jj] + xob) : hvB[jj];
            paA = fmaf(a1A, wav, paA); pbA = fmaf(hvA[jj], wbv, pbA);
            paB = fmaf(a1B, wav, paB); pbB = fmaf(hvB[jj], wbv, pbB);
        }
    }
    __syncthreads();          // all phase-C reads of tA/tX done
    #pragma unroll
    for (int jj = 0; jj < 8; ++jj) {
        tA[n * NPAD + jl + jj] = hvA[jj];
        tA[(n + 64) * NPAD + jl + jj] = hvB[jj];
    }
    if (sout != nullptr) {
        int w2i = (threadIdx.x >> 6) << 1;              // slot 0..14
        tX[n * 17 + w2i]            = paA;
        tX[n * 17 + w2i + 1]        = pbA;
        tX[(n + 64) * 17 + w2i]     = paB;
        tX[(n + 64) * 17 + w2i + 1] = pbB;
    }
    __syncthreads();
    for (int j = threadIdx.x; j < 2048; j += 512) {
        int r = j >> 4, c4 = (j & 15) << 2; int gr = r0 + r;
        if (gr < M) {
            int b = r * NPAD + c4;
            float4 ov = make_float4(tA[b], tA[b + 1], tA[b + 2], tA[b + 3]);
            *(float4*)(xout + (size_t)gr * 64 + c4) = ov;
        }
    }
    if (sout != nullptr && threadIdx.x < 128) {
        int r = threadIdx.x; int gr = r0 + r;
        if (gr < M) {
            float sa = 0.f, sb = 0.f;
            #pragma unroll
            for (int w = 0; w < 16; w += 2) { sa += tX[r * 17 + w]; sb += tX[r * 17 + w + 1]; }
            if (mode == 2) {
                sout[gr] = sa + dwb[0];
            } else {
                sout[gr] = sa; tout[gr] = sb;
            }
        }
    }
}

// ---------- readout: wave per graph, contiguous segment sum + relu ----------
__global__ __launch_bounds__(256) void k_seg_sum_relu(
    const float* __restrict__ x, const int* __restrict__ gst,
    float* __restrict__ outp, int G_)
{
    int g = (blockIdx.x * 256 + threadIdx.x) >> 6;
    int lane = threadIdx.x & 63;
    if (g >= G_) return;
    float S0 = 0.f, S1 = 0.f, S2 = 0.f, S3 = 0.f;
    int end = gst[g + 1];
    int i = gst[g];
    for (; i + 4 <= end; i += 4) {
        S0 += x[(size_t)i * 64 + lane];
        S1 += x[(size_t)(i + 1) * 64 + lane];
        S2 += x[(size_t)(i + 2) * 64 + lane];
        S3 += x[(size_t)(i + 3) * 64 + lane];
    }
    for (; i < end; ++i) S0 += x[(size_t)i * 64 + lane];
    outp[(size_t)g * 64 + lane] = fmaxf((S0 + S1) + (S2 + S3), 0.f);
}

// ---------- molecule attention: wave per graph, pipelined gather ----------
__global__ __launch_bounds__(256) void k_mol_gather(
    const float* __restrict__ xf, const float* __restrict__ cach,
    const float* __restrict__ stateIn, const int* __restrict__ gst,
    const float* __restrict__ dd,
    const float* __restrict__ maw, const float* __restrict__ mab,
    float* __restrict__ Agg, int G_)
{
    int g = (blockIdx.x * 256 + threadIdx.x) >> 6;
    int lane = threadIdx.x & 63;
    if (g >= G_) return;
    float o = stateIn[(size_t)g * 64 + lane];
    float og = wredsum(o * maw[lane]);
    float mb = mab[0];
    int beg = gst[g], end = gst[g + 1];
    float m = -INFINITY, d = 0.f, S = 0.f;
    for (int cs = beg; cs < end; cs += 64) {
        int cnt = min(64, end - cs);
        // issue first row-group loads before the score chain
        size_t rb = (size_t)cs * 64 + lane;
        float x0 = xf[rb],      c0 = cach[rb];
        float x1 = xf[rb + 64], c1 = cach[rb + 64];
        float x2 = xf[rb + 128], c2 = cach[rb + 128];
        float x3 = xf[rb + 192], c3 = cach[rb + 192];
        float sc_l = -INFINITY;
        if (lane < cnt) sc_l = leaky(og + dd[cs + lane] + mb);
        float cmax = wredmax(sc_l);
        float mn = fmaxf(m, cmax);
        float c = __expf(m - mn);
        float w_l = __expf(sc_l - mn);   // 0 for lanes >= cnt
        d = d * c + wredsum(w_l);
        S *= c;
        int cnt4 = (cnt + 3) & ~3;
        for (int l = 0; l < cnt4; l += 4) {
            int ln = (l + 4 < cnt4) ? l + 4 : 0;
            size_t rn = (size_t)(cs + ln) * 64 + lane;
            float y0 = xf[rn],       d0 = cach[rn];
            float y1 = xf[rn + 64],  d1 = cach[rn + 64];
            float y2 = xf[rn + 128], d2 = cach[rn + 128];
            float y3 = xf[rn + 192], d3 = cach[rn + 192];
            float w0 = bcastf(w_l, l),     w1 = bcastf(w_l, l + 1);
            float w2 = bcastf(w_l, l + 2), w3 = bcastf(w_l, l + 3);
            S = fmaf(w0, 0.5f * (x0 + c0), S);
            S = fmaf(w1, 0.5f * (x1 + c1), S);
            S = fmaf(w2, 0.5f * (x2 + c2), S);
            S = fmaf(w3, 0.5f * (x3 + c3), S);
            x0 = y0; c0 = d0; x1 = y1; c1 = d1;
            x2 = y2; c2 = d2; x3 = y3; c3 = d3;
        }
        m = mn;
    }
    Agg[(size_t)g * 64 + lane] = S / (d + 1e-16f);
}

// =====================================================================
extern "C" void kernel_launch(void* const* d_in, const int* in_sizes, int n_in,
                              void* d_out, int out_size, void* d_ws, size_t ws_size,
                              hipStream_t stream) {
    const float* raw           = (const float*)d_in[0];
    const int*   ei            = (const int*)d_in[1];
    const float* ea            = (const float*)d_in[2];
    const int*   batch         = (const int*)d_in[3];
    const float* lin1_w        = (const float*)d_in[4];
    const float* lin1_b        = (const float*)d_in[5];
    const float* gate_nl_w     = (const float*)d_in[6];
    const float* gate_nl_b     = (const float*)d_in[7];
    const float* gate_align_w  = (const float*)d_in[8];
    const float* gate_align_b  = (const float*)d_in[9];
    const float* gate_attend_w = (const float*)d_in[10];
    const float* gate_attend_b = (const float*)d_in[11];
    const float* conv_align_w  = (const float*)d_in[12];
    const float* conv_align_b  = (const float*)d_in[13];
    const float* conv_attend_w = (const float*)d_in[14];
    const float* conv_attend_b = (const float*)d_in[15];
    const float* gru_wih       = (const float*)d_in[16];
    const float* gru_whh       = (const float*)d_in[17];
    const float* gru_bih       = (const float*)d_in[18];
    const float* gru_bhh       = (const float*)d_in[19];
    const float* mol_align_w   = (const float*)d_in[20];
    const float* mol_align_b   = (const float*)d_in[21];
    const float* mol_attend_w  = (const float*)d_in[22];
    const float* mol_attend_b  = (const float*)d_in[23];
    const float* mol_wih       = (const float*)d_in[24];
    const float* mol_whh       = (const float*)d_in[25];
    const float* mol_bih       = (const float*)d_in[26];
    const float* mol_bhh       = (const float*)d_in[27];
    const float* lin2_w        = (const float*)d_in[28];
    const float* lin2_b        = (const float*)d_in[29];
    float* out = (float*)d_out;

    const int N = in_sizes[3];
    const int E = in_sizes[1] / 2;
    const int G = out_size;
    const size_t N64 = (size_t)N * 64;
    const size_t G64 = (size_t)G * 64;

    // ---- workspace layout ----
    float* f = (float*)d_ws;
    float* xA    = f;
    float* xB    = xA + N64;
    float* xD    = xB + N64;
    float* Agg   = xD + N64;
    float* u     = Agg + N64;
    float* sN    = u + N64;
    float* tN    = sN + N;
    float* dd    = tN + N;
    float* outS  = dd + N;
    float* outS2 = outS + G64;
    float* aggG  = outS2 + G64;
    int* row  = (int*)(aggG + G64);
    int* csrc = row + (N + 1);
    int* ceid = csrc + E;
    int* bsum = ceid + E;
    int* gst  = bsum + 512;
    int* deg = (int*)Agg;
    int* cur = deg + N;

    const int nb_node64  = (N + 63) / 64;
    const int nb_node128 = (N + 127) / 128;
    const int nb_edge   = (E + 255) / 256;
    const int nb_nodes  = (N + 255) / 256;
    const int nb_waveN  = (N + 3) / 4;
    const int nb_pairN  = ((N + 1) / 2 + 3) / 4;   // 2 nodes per wave
    const int nb_waveG  = (G + 3) / 4;
    const int nb_nodeG  = (G + 127) / 128;

    // ---- CSR build ----
    hipMemsetAsync(deg, 0, (size_t)N * 4, stream);
    k_hist<<<nb_edge, 256, 0, stream>>>(ei, deg, E);
    k_scan1<<<nb_nodes, 256, 0, stream>>>(deg, bsum, N);
    k_scan2<<<1, 512, 0, stream>>>(bsum, nb_nodes);
    k_scan3<<<nb_nodes, 256, 0, stream>>>(deg, bsum, row, cur, N, E);
    k_scatter<<<nb_edge, 256, 0, stream>>>(ei, cur, csrc, ceid, E);
    k_gbounds<<<nb_nodes, 256, 0, stream>>>(batch, gst, N, G);

    // ---- lin1 + gate node-part in ONE pass (+fused gate align dot -> sN) ----
    k_dense64_dual<<<nb_node64, 256, 0, stream>>>(raw, lin1_w, lin1_b,
                                                  gate_nl_w, gate_nl_b,
                                                  xA, u, N, gate_align_w, sN);

    // ---- layer 0: GATEConv (xA -> xB); emits align dots for GAT layer 0 ----
    k_gate_gather<<<nb_waveN, 256, 0, stream>>>(u, ea, row, csrc, ceid,
                                                gate_nl_w, gate_align_w, gate_align_b,
                                                sN, Agg, N);
    k_node_update<<<nb_node128, 512, 0, stream>>>(Agg, xA, gate_attend_w, gate_attend_b,
                                                  gru_wih, gru_whh, gru_bih, gru_bhh, xB, N,
                                                  conv_align_w, conv_align_w + 64, sN, tN, 0);

    // ---- GAT layer 0 (xB -> xD); emits align dots for GAT layer 1 ----
    k_gat_gather<<<nb_pairN, 256, 0, stream>>>(row, csrc, xB, sN, tN, conv_align_b, Agg, N);
    k_node_update<<<nb_node128, 512, 0, stream>>>(Agg, xB, conv_attend_w, conv_attend_b,
                                                  gru_wih + 12288, gru_whh + 12288,
                                                  gru_bih + 192, gru_bhh + 192, xD, N,
                                                  conv_align_w + 128, conv_align_w + 192, sN, tN, 0);

    // ---- GAT layer 1 (xD -> xA); emits mol dots dd0 -> dd, dd1 -> tN ----
    k_gat_gather<<<nb_pairN, 256, 0, stream>>>(row, csrc, xD, sN, tN, conv_align_b + 1, Agg, N);
    k_node_update<<<nb_node128, 512, 0, stream>>>(Agg, xD, conv_attend_w + 4096, conv_attend_b + 64,
                                                  gru_wih + 24576, gru_whh + 24576,
                                                  gru_bih + 384, gru_bhh + 384, xA, N,
                                                  mol_align_w + 64, mol_align_w + 64, dd, tN, 1);

    // ---- molecule readout ----
    k_seg_sum_relu<<<nb_waveG, 256, 0, stream>>>(xA, gst, outS, G);

    // t=0: cached = xD, dots = dd (0.5(xA+xD).maw2)
    k_mol_gather<<<nb_waveG, 256, 0, stream>>>(xA, xD, outS, gst, dd,
                                               mol_align_w, mol_align_b, aggG, G);
    k_node_update<<<nb_nodeG, 512, 0, stream>>>(aggG, outS, mol_attend_w, mol_attend_b,
                                                mol_wih, mol_whh, mol_bih, mol_bhh, outS2, G,
                                                nullptr, nullptr, nullptr, nullptr, 0);
    // t=1: cached = xA, dots = tN (xA.maw2); fused lin2 -> out
    k_mol_gather<<<nb_waveG, 256, 0, stream>>>(xA, xA, outS2, gst, tN,
                                               mol_align_w, mol_align_b, aggG, G);
    k_node_update<<<nb_nodeG, 512, 0, stream>>>(aggG, outS2, mol_attend_w, mol_attend_b,
                                                mol_wih, mol_whh, mol_bih, mol_bhh, outS, G,
                                                lin2_w, lin2_b, out, nullptr, 2);
}